// Round 13
// baseline (11024.851 us; speedup 1.0000x reference)
//
#include <hip/hip_runtime.h>
#include <hip/hip_bf16.h>
#include <hip/hip_cooperative_groups.h>
#include <math.h>

namespace cg = cooperative_groups;

// DIORA forward, MI355X. B=32, T=40, D_IN=1024, D=400.
// Round-9 structure; per-level chain replaced by two cooperative kernels
// (CGRID=256, guaranteed 1 block/CU co-residency). Launch return codes are
// CHECKED; on failure we fall back to the per-level launch chain (identical
// math). ws (bf16 unless noted):
//   hAB  (32,820,800)  [hA | hB]   hCb (32,820,400) score transform
//   hHin (32,820,400)  h_in bf16   hHout(32,820,400) h_out bf16
//   WinT (1200,400) K-major [Win_top^T|Win_bot^T|Sin^T]
//   WoutT(1200,400) K-major [Wout_top^T|Sout^T|Wout_bot^T]
//   WlT  (400,1024) K-major W_leaf^T; leafS(1280,400) fp32
// obuf (32,820,802) fp32 = d_out: [h_in 400 | s_in 1 | h_out 400 | s_out 1]

#define TLEN 40
#define DD 400
#define NCELL 820
#define STR 802
#define CGRID 256

typedef short bf16x8 __attribute__((ext_vector_type(8)));
typedef float f32x4 __attribute__((ext_vector_type(4)));

__host__ __device__ __forceinline__ int coff(int l) { return l * TLEN - (l * (l - 1)) / 2; }
__device__ __forceinline__ float bf2f(unsigned short u) {
    return __uint_as_float(((unsigned)u) << 16);
}
__device__ __forceinline__ unsigned short f2bf(float v) {
    __hip_bfloat16 h = __float2bfloat16(v);
    return *reinterpret_cast<unsigned short*>(&h);
}

// ---------------- weight prep ----------------
__global__ __launch_bounds__(256)
void prep_weights(const float* __restrict__ Win, const float* __restrict__ Sin,
                  const float* __restrict__ Wout, const float* __restrict__ Sout,
                  const float* __restrict__ Wl,
                  unsigned short* __restrict__ WinT, unsigned short* __restrict__ WoutT,
                  unsigned short* __restrict__ WlT)
{
    int n = blockIdx.x;                 // 0..2799
    if (n < 2400) {
        const float* src; int col; unsigned short* dst;
        if (n < 1200) {
            dst = WinT + (size_t)n * 400;
            if (n < 400)      { src = Win;             col = n; }
            else if (n < 800) { src = Win + 400 * 400; col = n - 400; }
            else              { src = Sin;             col = n - 800; }
        } else {
            int m = n - 1200;
            dst = WoutT + (size_t)m * 400;
            if (m < 400)      { src = Wout;             col = m; }
            else if (m < 800) { src = Sout;             col = m - 400; }
            else              { src = Wout + 400 * 400; col = m - 800; }
        }
        for (int k = threadIdx.x; k < 400; k += 256)
            dst[k] = f2bf(src[(size_t)k * 400 + col]);
    } else {
        int m = n - 2400;               // 0..399
        unsigned short* dst = WlT + (size_t)m * 1024;
        for (int k = threadIdx.x; k < 1024; k += 256)
            dst[k] = f2bf(Wl[(size_t)k * 400 + m]);
    }
}

// ---------------- bf16 MFMA GEMM tile: 64x128, BK=32, K=400 ----------------
__device__ void mgemm_tile(int bm, int bn,
                           const unsigned short* __restrict__ A,
                           const unsigned short* __restrict__ WT,
                           unsigned short* __restrict__ Cb, unsigned short* __restrict__ Cc,
                           int M, int N, int L, int cb, int co_b, int nsplit)
{
    __shared__ unsigned short As[64][40];
    __shared__ unsigned short Bs[128][40];
    const int tid = threadIdx.x;
    const int w = tid >> 6, lane = tid & 63;
    const int l15 = lane & 15, kb = (lane >> 4) * 8;

    const int ar = tid >> 2, ach = (tid & 3) * 8;
    const int rg = bm * 64 + ar;
    const unsigned short* Ap = nullptr;
    if (rg < M) { int b = rg / L, p = rg - b * L;
                  Ap = A + ((size_t)(b * NCELL) + cb + p) * 400; }

    const int bcol = tid & 127, bh = (tid >> 7) * 16;
    const int ng = bn * 128 + bcol;
    const unsigned short* Bp = (ng < N) ? WT + (size_t)ng * 400 : nullptr;

    f32x4 acc[4][2];
    #pragma unroll
    for (int r = 0; r < 4; ++r)
        #pragma unroll
        for (int c = 0; c < 2; ++c) { f32x4 z = {0.f, 0.f, 0.f, 0.f}; acc[r][c] = z; }

    for (int k0 = 0; k0 < 400; k0 += 32) {
        int4 av = {0, 0, 0, 0};
        if (Ap && (k0 + ach) < 400) av = *(const int4*)(Ap + k0 + ach);
        int4 bv0 = {0, 0, 0, 0}, bv1 = {0, 0, 0, 0};
        if (Bp && (k0 + bh) < 400) {
            bv0 = *(const int4*)(Bp + k0 + bh);
            bv1 = *(const int4*)(Bp + k0 + bh + 8);
        }
        __syncthreads();
        *(int4*)&As[ar][ach] = av;
        *(int4*)&Bs[bcol][bh] = bv0;
        *(int4*)&Bs[bcol][bh + 8] = bv1;
        __syncthreads();

        bf16x8 af[4], bf[2];
        #pragma unroll
        for (int r = 0; r < 4; ++r) af[r] = *(const bf16x8*)&As[r * 16 + l15][kb];
        #pragma unroll
        for (int c = 0; c < 2; ++c) bf[c] = *(const bf16x8*)&Bs[w * 32 + c * 16 + l15][kb];
        #pragma unroll
        for (int r = 0; r < 4; ++r)
            #pragma unroll
            for (int c = 0; c < 2; ++c)
                acc[r][c] = __builtin_amdgcn_mfma_f32_16x16x32_bf16(af[r], bf[c], acc[r][c], 0, 0, 0);
    }
    __syncthreads();   // protect LDS before next tile iteration

    const int rowb = (lane >> 4) * 4;
    #pragma unroll
    for (int r = 0; r < 4; ++r) {
        #pragma unroll
        for (int c = 0; c < 2; ++c) {
            int gcol = bn * 128 + w * 32 + c * 16 + l15;
            if (gcol >= N) continue;
            #pragma unroll
            for (int reg = 0; reg < 4; ++reg) {
                int rr = bm * 64 + r * 16 + rowb + reg;
                if (rr >= M) continue;
                int b = rr / L, p = rr - b * L;
                size_t cell = (size_t)(b * NCELL) + cb + p;
                unsigned short v = f2bf(acc[r][c][reg]);
                if (gcol < nsplit) Cb[cell * 800 + co_b + gcol] = v;
                else               Cc[cell * 400 + (gcol - nsplit)] = v;
            }
        }
    }
}

__global__ __launch_bounds__(256)
void mgemm_kernel(const unsigned short* __restrict__ A, const unsigned short* __restrict__ WT,
                  unsigned short* __restrict__ Cb, unsigned short* __restrict__ Cc,
                  int M, int N, int L, int cb, int co_b, int nsplit)
{
    mgemm_tile(blockIdx.x, blockIdx.y, A, WT, Cb, Cc, M, N, L, cb, co_b, nsplit);
}

// ---------------- leaf MFMA GEMM ----------------
__global__ __launch_bounds__(256)
void mleaf(const float* __restrict__ x, const unsigned short* __restrict__ WlT,
           const float* __restrict__ bias, float* __restrict__ leafS)
{
    __shared__ unsigned short As[64][40];
    __shared__ unsigned short Bs[128][40];
    const int tid = threadIdx.x;
    const int bm = blockIdx.x, bn = blockIdx.y;
    const int w = tid >> 6, lane = tid & 63;
    const int l15 = lane & 15, kb = (lane >> 4) * 8;

    const int ar = tid >> 2, ach = (tid & 3) * 8;
    const float* Ap = x + (size_t)(bm * 64 + ar) * 1024;

    const int bcol = tid & 127, bh = (tid >> 7) * 16;
    const int ng = bn * 128 + bcol;
    const unsigned short* Bp = (ng < 400) ? WlT + (size_t)ng * 1024 : nullptr;

    f32x4 acc[4][2];
    #pragma unroll
    for (int r = 0; r < 4; ++r)
        #pragma unroll
        for (int c = 0; c < 2; ++c) { f32x4 z = {0.f, 0.f, 0.f, 0.f}; acc[r][c] = z; }

    for (int k0 = 0; k0 < 1024; k0 += 32) {
        float4 p0 = *(const float4*)(Ap + k0 + ach);
        float4 p1 = *(const float4*)(Ap + k0 + ach + 4);
        unsigned short av[8];
        av[0] = f2bf(p0.x); av[1] = f2bf(p0.y); av[2] = f2bf(p0.z); av[3] = f2bf(p0.w);
        av[4] = f2bf(p1.x); av[5] = f2bf(p1.y); av[6] = f2bf(p1.z); av[7] = f2bf(p1.w);
        int4 bv0 = {0, 0, 0, 0}, bv1 = {0, 0, 0, 0};
        if (Bp) {
            bv0 = *(const int4*)(Bp + k0 + bh);
            bv1 = *(const int4*)(Bp + k0 + bh + 8);
        }
        __syncthreads();
        *(int4*)&As[ar][ach] = *(const int4*)av;
        *(int4*)&Bs[bcol][bh] = bv0;
        *(int4*)&Bs[bcol][bh + 8] = bv1;
        __syncthreads();

        bf16x8 af[4], bf[2];
        #pragma unroll
        for (int r = 0; r < 4; ++r) af[r] = *(const bf16x8*)&As[r * 16 + l15][kb];
        #pragma unroll
        for (int c = 0; c < 2; ++c) bf[c] = *(const bf16x8*)&Bs[w * 32 + c * 16 + l15][kb];
        #pragma unroll
        for (int r = 0; r < 4; ++r)
            #pragma unroll
            for (int c = 0; c < 2; ++c)
                acc[r][c] = __builtin_amdgcn_mfma_f32_16x16x32_bf16(af[r], bf[c], acc[r][c], 0, 0, 0);
    }

    const int rowb = (lane >> 4) * 4;
    #pragma unroll
    for (int r = 0; r < 4; ++r) {
        #pragma unroll
        for (int c = 0; c < 2; ++c) {
            int gcol = bn * 128 + w * 32 + c * 16 + l15;
            if (gcol >= 400) continue;
            float bv = bias[gcol];
            #pragma unroll
            for (int reg = 0; reg < 4; ++reg) {
                int rr = bm * 64 + r * 16 + rowb + reg;
                leafS[(size_t)rr * 400 + gcol] = fmaxf(acc[r][c][reg] + bv, 0.f);
            }
        }
    }
}

// ---------------- normalize leaf rows ----------
__global__ __launch_bounds__(256)
void unit_leaf(float* obuf, const float* __restrict__ leafS, unsigned short* __restrict__ hHin)
{
    int w = threadIdx.x >> 6, lane = threadIdx.x & 63;
    int r = blockIdx.x * 4 + w;                 // 0..1279 = (b, pos)
    int b = r / TLEN, pos = r - b * TLEN;
    const float* t = leafS + (size_t)r * 400;
    float ss = 0.f;
    for (int f = lane; f < DD; f += 64) { float v = t[f]; ss += v * v; }
    #pragma unroll
    for (int o = 32; o; o >>= 1) ss += __shfl_xor(ss, o);
    float rinv = 1.f / (sqrtf(ss) + 1e-8f);
    size_t orow = ((size_t)b * NCELL + pos) * STR;
    size_t hrow = ((size_t)b * NCELL + pos) * 400;
    for (int f = lane; f < DD; f += 64) {
        float v = t[f] * rinv;
        obuf[orow + f] = v;
        hHin[hrow + f] = f2bf(v);
    }
    if (lane == 0) obuf[orow + DD] = 0.f;       // s_in(leaf)=0
}

// ---------------- per-cell compose (round-9 proven body) ----------------
template<int INSIDE>
__device__ void compose_cell(int lv, int job, float* obuf,
                             const unsigned short* __restrict__ hAB,
                             const unsigned short* __restrict__ hCb,
                             const unsigned short* __restrict__ hHin,
                             unsigned short* __restrict__ hHw,
                             const float* __restrict__ bias)
{
    const int nk  = INSIDE ? lv : (TLEN - 1 - lv);
    const int b   = job & 31;
    const int pos = job >> 5;
    const int cell = coff(lv) + pos;
    const int tid = threadIdx.x;
    const int sA  = INSIDE ? DD : (STR - 1);  // s-term offset for i1 in obuf

    __shared__ int   o1s[TLEN], o2s[TLEN], c1s[TLEN], h2s[TLEN], q1s[TLEN], q2s[TLEN];
    __shared__ float sbs[TLEN], ps[TLEN];
    __shared__ float bsh[DD];
    __shared__ float hnew[DD];
    __shared__ float red[4];
    __shared__ float sh_snew;

    if (tid < nk) {
        int k = tid, i1, i2;
        if (INSIDE) {
            i1 = coff(k) + pos;
            i2 = coff(lv - k - 1) + pos + k + 1;
        } else {
            if (k < pos) { i1 = coff(lv + k + 1) + pos - k - 1; i2 = coff(k) + pos - k - 1; }
            else         { int j = k - pos; i1 = coff(lv + j + 1) + pos; i2 = coff(j) + pos + lv + 1; }
        }
        o1s[k] = (b * NCELL + i1) * 800;        // hA
        o2s[k] = (b * NCELL + i2) * 800 + 400;  // hB
        c1s[k] = (b * NCELL + i1) * 400;        // hCb (score)
        h2s[k] = (b * NCELL + i2) * 400;        // hHin (score)
        q1s[k] = (b * NCELL + i1) * STR;
        q2s[k] = (b * NCELL + i2) * STR;
    }
    for (int f = tid; f < DD; f += 256) bsh[f] = bias[f];
    __syncthreads();

    // Phase A: scores sb_k = dot(hCb[i1], hHin[i2]) + s1 + s2
    {
        const int g = tid >> 4, gl = tid & 15;
        for (int k = g; k < nk; k += 16) {
            const unsigned short* v1 = hCb + c1s[k];
            const unsigned short* v2 = hHin + h2s[k];
            float acc = 0.f;
            for (int j = gl * 4; j < 400; j += 64) {
                ushort4 a = *(const ushort4*)(v1 + j);
                ushort4 c = *(const ushort4*)(v2 + j);
                acc += bf2f(a.x) * bf2f(c.x) + bf2f(a.y) * bf2f(c.y)
                     + bf2f(a.z) * bf2f(c.z) + bf2f(a.w) * bf2f(c.w);
            }
            acc += __shfl_xor(acc, 8);
            acc += __shfl_xor(acc, 4);
            acc += __shfl_xor(acc, 2);
            acc += __shfl_xor(acc, 1);
            if (gl == 0)
                sbs[k] = acc + obuf[q1s[k] + sA] + obuf[q2s[k] + DD];
        }
    }
    __syncthreads();

    // softmax (wave 0), also s_new = sum p*sb
    if (tid < 64) {
        float v = (tid < nk) ? sbs[tid] : -INFINITY;
        float m = v;
        #pragma unroll
        for (int o = 32; o; o >>= 1) m = fmaxf(m, __shfl_xor(m, o));
        float e = (tid < nk) ? __expf(v - m) : 0.f;
        float s = e;
        #pragma unroll
        for (int o = 32; o; o >>= 1) s += __shfl_xor(s, o);
        float p = e / s;
        if (tid < nk) ps[tid] = p;
        float pv = (tid < nk) ? p * v : 0.f;
        #pragma unroll
        for (int o = 32; o; o >>= 1) pv += __shfl_xor(pv, o);
        if (tid == 0) sh_snew = pv;
    }
    __syncthreads();

    // Phase B: h_new = sum_k p_k * relu(hA[i1] + hB[i2] + bias)
    if (tid < 200) {
        const int f = 2 * tid;
        const float bf0 = bsh[f], bf1 = bsh[f + 1];
        float ax = 0.f, ay = 0.f;
        #pragma unroll 4
        for (int k = 0; k < nk; ++k) {
            ushort2 a = *(const ushort2*)(hAB + o1s[k] + f);
            ushort2 c = *(const ushort2*)(hAB + o2s[k] + f);
            float p = ps[k];
            ax += p * fmaxf(bf2f(a.x) + bf2f(c.x) + bf0, 0.f);
            ay += p * fmaxf(bf2f(a.y) + bf2f(c.y) + bf1, 0.f);
        }
        hnew[f] = ax; hnew[f + 1] = ay;
    }
    __syncthreads();

    // norm
    float ss = 0.f;
    for (int f = tid; f < DD; f += 256) { float v = hnew[f]; ss += v * v; }
    #pragma unroll
    for (int o = 32; o; o >>= 1) ss += __shfl_xor(ss, o);
    if ((tid & 63) == 0) red[tid >> 6] = ss;
    __syncthreads();
    float rinv = 1.f / (sqrtf(red[0] + red[1] + red[2] + red[3]) + 1e-8f);

    const int hoff = INSIDE ? 0 : (DD + 1);
    const int soff = INSIDE ? DD : (STR - 1);
    size_t orow = ((size_t)(b * NCELL) + cell) * STR;
    size_t hrow = ((size_t)(b * NCELL) + cell) * 400;
    for (int f = tid; f < DD; f += 256) {
        float v = hnew[f] * rinv;
        obuf[orow + hoff + f] = v;
        hHw[hrow + f] = f2bf(v);
    }
    if (tid == 0) obuf[orow + soff] = sh_snew;
    __syncthreads();   // protect shared arrays before next job
}

// per-level fallback wrappers
template<int INSIDE>
__global__ __launch_bounds__(256)
void compose_wrap(int lv, float* obuf, const unsigned short* hAB,
                  const unsigned short* hCb, const unsigned short* hHin,
                  unsigned short* hHw, const float* bias)
{
    compose_cell<INSIDE>(lv, blockIdx.x, obuf, hAB, hCb, hHin, hHw, bias);
}

// ---------------- persistent cooperative passes ----------------
__global__ __launch_bounds__(256)
void inside_pass(float* obuf, unsigned short* hAB, unsigned short* hCb,
                 unsigned short* hHin, const unsigned short* WinT, const float* bin)
{
    cg::grid_group grid = cg::this_grid();
    for (int lv = 0; lv < TLEN; ++lv) {
        const int L = TLEN - lv, cb = coff(lv);
        if (lv > 0) {
            const int jobs = L * 32;
            for (int j = blockIdx.x; j < jobs; j += gridDim.x)
                compose_cell<1>(lv, j, obuf, hAB, hCb, hHin, hHin, bin);
            __threadfence();
            grid.sync();
        }
        if (lv < TLEN - 1) {
            const int M = L * 32;
            const int nbm = (M + 63) / 64;
            const int tiles = nbm * 10;          // N=1200
            for (int t = blockIdx.x; t < tiles; t += gridDim.x)
                mgemm_tile(t % nbm, t / nbm, hHin, WinT, hAB, hCb, M, 1200, L, cb, 0, 800);
            __threadfence();
            grid.sync();
        }
    }
}

__global__ __launch_bounds__(256)
void outside_pass(float* obuf, unsigned short* hAB, unsigned short* hCb,
                  const unsigned short* hHin, unsigned short* hHout,
                  const unsigned short* WoutT, const float* bout)
{
    cg::grid_group grid = cg::this_grid();
    for (int lv = TLEN - 2; lv >= 0; --lv) {
        const int L = TLEN - lv, cb = coff(lv);
        const int jobs = L * 32;
        for (int j = blockIdx.x; j < jobs; j += gridDim.x)
            compose_cell<0>(lv, j, obuf, hAB, hCb, hHin, hHout, bout);
        __threadfence();
        grid.sync();
        if (lv > 0) {
            const int M = L * 32;
            const int nbm = (M + 63) / 64;
            const int tiles = nbm * 7;           // N=800
            for (int t = blockIdx.x; t < tiles; t += gridDim.x)
                mgemm_tile(t % nbm, t / nbm, hHout, WoutT, hAB, hCb, M, 800, L, cb, 0, 400);
            __threadfence();
            grid.sync();
        }
    }
}

// ---- root: hAB[root][0:400)=u@Wout_top, hCb[root]=u@Sout, obuf h_out/s_out --
__global__ __launch_bounds__(256)
void root_trans(const float* __restrict__ rooth, const float* __restrict__ Wout,
                const float* __restrict__ Sout,
                unsigned short* __restrict__ hAB, unsigned short* __restrict__ hCb,
                float* obuf)
{
    const int tid = threadIdx.x;
    __shared__ float u[DD];
    __shared__ float red[4];
    __shared__ float part[4][64];
    float ss = 0.f;
    for (int f = tid; f < DD; f += 256) { float v = rooth[f]; ss += v * v; }
    #pragma unroll
    for (int o = 32; o; o >>= 1) ss += __shfl_xor(ss, o);
    if ((tid & 63) == 0) red[tid >> 6] = ss;
    __syncthreads();
    float rinv = 1.f / (sqrtf(red[0] + red[1] + red[2] + red[3]) + 1e-8f);
    for (int f = tid; f < DD; f += 256) u[f] = rooth[f] * rinv;
    __syncthreads();

    const int w = tid >> 6, lane = tid & 63;
    const int n = blockIdx.x * 64 + lane;
    float acc = 0.f;
    if (n < 800) {
        int mat = n / DD;
        const float* Mp = mat ? Sout : Wout;
        int c = n - mat * DD;
        #pragma unroll 4
        for (int k = w * 100; k < w * 100 + 100; ++k) acc += u[k] * Mp[(size_t)k * DD + c];
    }
    part[w][lane] = acc;
    if (w == 1 && n < 400) {
        for (int b = 0; b < 32; ++b)
            obuf[((size_t)b * NCELL + NCELL - 1) * STR + DD + 1 + n] = u[n];
    }
    if (w == 2 && blockIdx.x == 0 && lane < 32)
        obuf[((size_t)lane * NCELL + NCELL - 1) * STR + (STR - 1)] = 0.f;
    __syncthreads();
    if (w == 0 && n < 800) {
        float v = part[0][lane] + part[1][lane] + part[2][lane] + part[3][lane];
        unsigned short bv = f2bf(v);
        if (n < 400) {
            for (int b = 0; b < 32; ++b)
                hAB[((size_t)b * NCELL + NCELL - 1) * 800 + n] = bv;
        } else {
            for (int b = 0; b < 32; ++b)
                hCb[((size_t)b * NCELL + NCELL - 1) * 400 + (n - 400)] = bv;
        }
    }
}

extern "C" void kernel_launch(void* const* d_in, const int* in_sizes, int n_in,
                              void* d_out, int out_size, void* d_ws, size_t ws_size,
                              hipStream_t stream)
{
    const float* x     = (const float*)d_in[0];
    const float* Wl    = (const float*)d_in[1];
    const float* blf   = (const float*)d_in[2];
    const float* Win   = (const float*)d_in[3];
    const float* bin   = (const float*)d_in[4];
    const float* Sin   = (const float*)d_in[5];
    const float* Wout  = (const float*)d_in[6];
    const float* bout  = (const float*)d_in[7];
    const float* Sout  = (const float*)d_in[8];
    const float* rooth = (const float*)d_in[9];

    float* obuf = (float*)d_out;
    const size_t CELLS = (size_t)32 * NCELL;
    unsigned short* hAB   = (unsigned short*)d_ws;          // 42 MB
    unsigned short* hCb   = hAB   + CELLS * 800;            // 21 MB
    unsigned short* hHin  = hCb   + CELLS * 400;            // 21 MB
    unsigned short* hHout = hHin  + CELLS * 400;            // 21 MB
    unsigned short* WinT  = hHout + CELLS * 400;            // 0.96 MB
    unsigned short* WoutT = WinT  + (size_t)1200 * 400;     // 0.96 MB
    unsigned short* WlT   = WoutT + (size_t)1200 * 400;     // 0.82 MB
    float* leafS = (float*)(WlT + (size_t)400 * 1024);      // 2 MB fp32

    prep_weights<<<2800, 256, 0, stream>>>(Win, Sin, Wout, Sout, Wl, WinT, WoutT, WlT);

    // leaf projection (MFMA): relu(x @ W_leaf + b) -> leafS
    mleaf<<<dim3(20, 4), 256, 0, stream>>>(x, WlT, blf, leafS);
    unit_leaf<<<320, 256, 0, stream>>>(obuf, leafS, hHin);

    // inside pass: cooperative if possible, else per-level chain
    {
        void* args[] = { (void*)&obuf, (void*)&hAB, (void*)&hCb, (void*)&hHin,
                         (void*)&WinT, (void*)&bin };
        hipError_t e = hipLaunchCooperativeKernel((const void*)inside_pass,
                                                  dim3(CGRID), dim3(256), args, 0, stream);
        if (e != hipSuccess) {
            for (int lv = 0; lv < TLEN; ++lv) {
                int L = TLEN - lv, cb = coff(lv);
                if (lv > 0)
                    compose_wrap<1><<<L * 32, 256, 0, stream>>>(lv, obuf, hAB, hCb,
                                                                hHin, hHin, bin);
                if (lv < TLEN - 1)
                    mgemm_kernel<<<dim3((L * 32 + 63) / 64, 10), 256, 0, stream>>>(
                        hHin, WinT, hAB, hCb, L * 32, 1200, L, cb, 0, 800);
            }
        }
    }

    // prep: hAB[:, 400:800) = h_in @ W_out_bot for ALL cells (parallel GEMM)
    mgemm_kernel<<<dim3(410, 4), 256, 0, stream>>>(hHin, WoutT + (size_t)800 * 400,
                                                   hAB, hCb, 32 * NCELL, 400, NCELL,
                                                   0, 400, 400);
    root_trans<<<13, 256, 0, stream>>>(rooth, Wout, Sout, hAB, hCb, obuf);

    // outside pass: cooperative if possible, else per-level chain
    {
        void* args[] = { (void*)&obuf, (void*)&hAB, (void*)&hCb, (void*)&hHin,
                         (void*)&hHout, (void*)&WoutT, (void*)&bout };
        hipError_t e = hipLaunchCooperativeKernel((const void*)outside_pass,
                                                  dim3(CGRID), dim3(256), args, 0, stream);
        if (e != hipSuccess) {
            for (int lv = TLEN - 2; lv >= 0; --lv) {
                int L = TLEN - lv, cb = coff(lv);
                compose_wrap<0><<<L * 32, 256, 0, stream>>>(lv, obuf, hAB, hCb,
                                                            hHin, hHout, bout);
                if (lv > 0)
                    mgemm_kernel<<<dim3((L * 32 + 63) / 64, 7), 256, 0, stream>>>(
                        hHout, WoutT, hAB, hCb, L * 32, 800, L, cb, 0, 400);
            }
        }
    }
}

// Round 14
// 2039.085 us; speedup vs baseline: 5.4068x; 5.4068x over previous
//
#include <hip/hip_runtime.h>
#include <hip/hip_bf16.h>
#include <math.h>

// DIORA forward, MI355X. B=32, T=40, D_IN=1024, D=400.
// Round-9 champion structure (per-level launches, BK=32 mgemm N=1200 inside,
// separate parallel prep GEMM) + double-buffered LDS in mgemm (13 barriers
// instead of 26, global loads overlapped with MFMA) + merged root kernel.
// ws (bf16 unless noted):
//   hAB  (32,820,800)  [hA | hB]   hCb (32,820,400) score transform
//   hHin (32,820,400)  h_in bf16   hHout(32,820,400) h_out bf16
//   WinT (1200,400) K-major [Win_top^T|Win_bot^T|Sin^T]
//   WoutT(1200,400) K-major [Wout_top^T|Sout^T|Wout_bot^T]
//   WlT  (400,1024) K-major W_leaf^T; leafS(1280,400) fp32
// obuf (32,820,802) fp32 = d_out: [h_in 400 | s_in 1 | h_out 400 | s_out 1]

#define TLEN 40
#define DD 400
#define NCELL 820
#define STR 802

typedef short bf16x8 __attribute__((ext_vector_type(8)));
typedef float f32x4 __attribute__((ext_vector_type(4)));

__host__ __device__ __forceinline__ int coff(int l) { return l * TLEN - (l * (l - 1)) / 2; }
__device__ __forceinline__ float bf2f(unsigned short u) {
    return __uint_as_float(((unsigned)u) << 16);
}
__device__ __forceinline__ unsigned short f2bf(float v) {
    __hip_bfloat16 h = __float2bfloat16(v);
    return *reinterpret_cast<unsigned short*>(&h);
}

// ---------------- weight prep: bf16 K-major transposed copies ----------------
__global__ __launch_bounds__(256)
void prep_weights(const float* __restrict__ Win, const float* __restrict__ Sin,
                  const float* __restrict__ Wout, const float* __restrict__ Sout,
                  const float* __restrict__ Wl,
                  unsigned short* __restrict__ WinT, unsigned short* __restrict__ WoutT,
                  unsigned short* __restrict__ WlT)
{
    int n = blockIdx.x;                 // 0..2799
    if (n < 2400) {
        const float* src; int col; unsigned short* dst;
        if (n < 1200) {
            dst = WinT + (size_t)n * 400;
            if (n < 400)      { src = Win;             col = n; }
            else if (n < 800) { src = Win + 400 * 400; col = n - 400; }
            else              { src = Sin;             col = n - 800; }
        } else {
            int m = n - 1200;
            dst = WoutT + (size_t)m * 400;
            if (m < 400)      { src = Wout;             col = m; }
            else if (m < 800) { src = Sout;             col = m - 400; }
            else              { src = Wout + 400 * 400; col = m - 800; }
        }
        for (int k = threadIdx.x; k < 400; k += 256)
            dst[k] = f2bf(src[(size_t)k * 400 + col]);
    } else {
        int m = n - 2400;               // 0..399
        unsigned short* dst = WlT + (size_t)m * 1024;
        for (int k = threadIdx.x; k < 1024; k += 256)
            dst[k] = f2bf(Wl[(size_t)k * 400 + m]);
    }
}

// ------- bf16 MFMA GEMM: 64x128 tile, BK=32, K=400, double-buffered LDS ------
// A = bf16 cell rows. Row r -> b=r/L, p=r%L, cell=cb+p.
// B = WT (bf16, K-major). Output: n<nsplit -> Cb[cell*800+co_b+n] else
// Cc[cell*400 + n-nsplit].
__global__ __launch_bounds__(256)
void mgemm(const unsigned short* __restrict__ A, const unsigned short* __restrict__ WT,
           unsigned short* __restrict__ Cb, unsigned short* __restrict__ Cc,
           int M, int N, int L, int cb, int co_b, int nsplit)
{
    __shared__ unsigned short As[2][64][40];
    __shared__ unsigned short Bs[2][128][40];
    const int tid = threadIdx.x;
    const int bm = blockIdx.x, bn = blockIdx.y;
    const int w = tid >> 6, lane = tid & 63;
    const int l15 = lane & 15, kb = (lane >> 4) * 8;

    const int ar = tid >> 2, ach = (tid & 3) * 8;
    const int rg = bm * 64 + ar;
    const unsigned short* Ap = nullptr;
    if (rg < M) { int b = rg / L, p = rg - b * L;
                  Ap = A + ((size_t)(b * NCELL) + cb + p) * 400; }

    const int bcol = tid & 127, bh = (tid >> 7) * 16;
    const int ng = bn * 128 + bcol;
    const unsigned short* Bp = (ng < N) ? WT + (size_t)ng * 400 : nullptr;

    f32x4 acc[4][2];
    #pragma unroll
    for (int r = 0; r < 4; ++r)
        #pragma unroll
        for (int c = 0; c < 2; ++c) { f32x4 z = {0.f, 0.f, 0.f, 0.f}; acc[r][c] = z; }

    // prologue: stage k0=0 into buffer 0
    {
        int4 av = {0, 0, 0, 0};
        if (Ap && ach < 400) av = *(const int4*)(Ap + ach);
        int4 bv0 = {0, 0, 0, 0}, bv1 = {0, 0, 0, 0};
        if (Bp && bh < 400) {
            bv0 = *(const int4*)(Bp + bh);
            bv1 = *(const int4*)(Bp + bh + 8);
        }
        *(int4*)&As[0][ar][ach] = av;
        *(int4*)&Bs[0][bcol][bh] = bv0;
        *(int4*)&Bs[0][bcol][bh + 8] = bv1;
    }
    __syncthreads();

    int cur = 0;
    for (int k0 = 0; k0 < 400; k0 += 32) {
        const int nxt = k0 + 32;
        // issue next chunk's global loads (complete under the MFMAs below)
        int4 av = {0, 0, 0, 0}, bv0 = {0, 0, 0, 0}, bv1 = {0, 0, 0, 0};
        if (nxt < 400) {
            if (Ap && (nxt + ach) < 400) av = *(const int4*)(Ap + nxt + ach);
            if (Bp && (nxt + bh) < 400) {
                bv0 = *(const int4*)(Bp + nxt + bh);
                bv1 = *(const int4*)(Bp + nxt + bh + 8);
            }
        }

        bf16x8 af[4], bf[2];
        #pragma unroll
        for (int r = 0; r < 4; ++r) af[r] = *(const bf16x8*)&As[cur][r * 16 + l15][kb];
        #pragma unroll
        for (int c = 0; c < 2; ++c) bf[c] = *(const bf16x8*)&Bs[cur][w * 32 + c * 16 + l15][kb];
        #pragma unroll
        for (int r = 0; r < 4; ++r)
            #pragma unroll
            for (int c = 0; c < 2; ++c)
                acc[r][c] = __builtin_amdgcn_mfma_f32_16x16x32_bf16(af[r], bf[c], acc[r][c], 0, 0, 0);

        if (nxt < 400) {
            *(int4*)&As[cur ^ 1][ar][ach] = av;
            *(int4*)&Bs[cur ^ 1][bcol][bh] = bv0;
            *(int4*)&Bs[cur ^ 1][bcol][bh + 8] = bv1;
            __syncthreads();
        }
        cur ^= 1;
    }

    const int rowb = (lane >> 4) * 4;
    #pragma unroll
    for (int r = 0; r < 4; ++r) {
        #pragma unroll
        for (int c = 0; c < 2; ++c) {
            int gcol = bn * 128 + w * 32 + c * 16 + l15;
            if (gcol >= N) continue;
            #pragma unroll
            for (int reg = 0; reg < 4; ++reg) {
                int rr = bm * 64 + r * 16 + rowb + reg;
                if (rr >= M) continue;
                int b = rr / L, p = rr - b * L;
                size_t cell = (size_t)(b * NCELL) + cb + p;
                unsigned short v = f2bf(acc[r][c][reg]);
                if (gcol < nsplit) Cb[cell * 800 + co_b + gcol] = v;
                else               Cc[cell * 400 + (gcol - nsplit)] = v;
            }
        }
    }
}

// ---------------- leaf MFMA GEMM: x(fp32,K=1024) @ WlT -> leafS fp32 ---------
__global__ __launch_bounds__(256)
void mleaf(const float* __restrict__ x, const unsigned short* __restrict__ WlT,
           const float* __restrict__ bias, float* __restrict__ leafS)
{
    __shared__ unsigned short As[64][40];
    __shared__ unsigned short Bs[128][40];
    const int tid = threadIdx.x;
    const int bm = blockIdx.x, bn = blockIdx.y;
    const int w = tid >> 6, lane = tid & 63;
    const int l15 = lane & 15, kb = (lane >> 4) * 8;

    const int ar = tid >> 2, ach = (tid & 3) * 8;
    const float* Ap = x + (size_t)(bm * 64 + ar) * 1024;

    const int bcol = tid & 127, bh = (tid >> 7) * 16;
    const int ng = bn * 128 + bcol;
    const unsigned short* Bp = (ng < 400) ? WlT + (size_t)ng * 1024 : nullptr;

    f32x4 acc[4][2];
    #pragma unroll
    for (int r = 0; r < 4; ++r)
        #pragma unroll
        for (int c = 0; c < 2; ++c) { f32x4 z = {0.f, 0.f, 0.f, 0.f}; acc[r][c] = z; }

    for (int k0 = 0; k0 < 1024; k0 += 32) {
        float4 p0 = *(const float4*)(Ap + k0 + ach);
        float4 p1 = *(const float4*)(Ap + k0 + ach + 4);
        unsigned short av[8];
        av[0] = f2bf(p0.x); av[1] = f2bf(p0.y); av[2] = f2bf(p0.z); av[3] = f2bf(p0.w);
        av[4] = f2bf(p1.x); av[5] = f2bf(p1.y); av[6] = f2bf(p1.z); av[7] = f2bf(p1.w);
        int4 bv0 = {0, 0, 0, 0}, bv1 = {0, 0, 0, 0};
        if (Bp) {
            bv0 = *(const int4*)(Bp + k0 + bh);
            bv1 = *(const int4*)(Bp + k0 + bh + 8);
        }
        __syncthreads();
        *(int4*)&As[ar][ach] = *(const int4*)av;
        *(int4*)&Bs[bcol][bh] = bv0;
        *(int4*)&Bs[bcol][bh + 8] = bv1;
        __syncthreads();

        bf16x8 af[4], bf[2];
        #pragma unroll
        for (int r = 0; r < 4; ++r) af[r] = *(const bf16x8*)&As[r * 16 + l15][kb];
        #pragma unroll
        for (int c = 0; c < 2; ++c) bf[c] = *(const bf16x8*)&Bs[w * 32 + c * 16 + l15][kb];
        #pragma unroll
        for (int r = 0; r < 4; ++r)
            #pragma unroll
            for (int c = 0; c < 2; ++c)
                acc[r][c] = __builtin_amdgcn_mfma_f32_16x16x32_bf16(af[r], bf[c], acc[r][c], 0, 0, 0);
    }

    const int rowb = (lane >> 4) * 4;
    #pragma unroll
    for (int r = 0; r < 4; ++r) {
        #pragma unroll
        for (int c = 0; c < 2; ++c) {
            int gcol = bn * 128 + w * 32 + c * 16 + l15;
            if (gcol >= 400) continue;
            float bv = bias[gcol];
            #pragma unroll
            for (int reg = 0; reg < 4; ++reg) {
                int rr = bm * 64 + r * 16 + rowb + reg;
                leafS[(size_t)rr * 400 + gcol] = fmaxf(acc[r][c][reg] + bv, 0.f);
            }
        }
    }
}

// ---------------- normalize leaf rows ----------
__global__ __launch_bounds__(256)
void unit_leaf(float* obuf, const float* __restrict__ leafS, unsigned short* __restrict__ hHin)
{
    int w = threadIdx.x >> 6, lane = threadIdx.x & 63;
    int r = blockIdx.x * 4 + w;                 // 0..1279 = (b, pos)
    int b = r / TLEN, pos = r - b * TLEN;
    const float* t = leafS + (size_t)r * 400;
    float ss = 0.f;
    for (int f = lane; f < DD; f += 64) { float v = t[f]; ss += v * v; }
    #pragma unroll
    for (int o = 32; o; o >>= 1) ss += __shfl_xor(ss, o);
    float rinv = 1.f / (sqrtf(ss) + 1e-8f);
    size_t orow = ((size_t)b * NCELL + pos) * STR;
    size_t hrow = ((size_t)b * NCELL + pos) * 400;
    for (int f = lane; f < DD; f += 64) {
        float v = t[f] * rinv;
        obuf[orow + f] = v;
        hHin[hrow + f] = f2bf(v);
    }
    if (lane == 0) obuf[orow + DD] = 0.f;       // s_in(leaf)=0
}

// ---------------- per-level compose (round-9 proven) ----------------
template<int INSIDE>
__global__ __launch_bounds__(256)
void compose_kernel(int lv, float* obuf, const unsigned short* __restrict__ hAB,
                    const unsigned short* __restrict__ hCb,
                    const unsigned short* __restrict__ hHin,
                    unsigned short* __restrict__ hHw,
                    const float* __restrict__ bias)
{
    const int nk  = INSIDE ? lv : (TLEN - 1 - lv);
    const int b   = blockIdx.x & 31;
    const int pos = blockIdx.x >> 5;
    const int cell = coff(lv) + pos;
    const int tid = threadIdx.x;
    const int sA  = INSIDE ? DD : (STR - 1);  // s-term offset for i1 in obuf

    __shared__ int   o1s[TLEN], o2s[TLEN], c1s[TLEN], h2s[TLEN], q1s[TLEN], q2s[TLEN];
    __shared__ float sbs[TLEN], ps[TLEN];
    __shared__ float bsh[DD];
    __shared__ float hnew[DD];
    __shared__ float red[4];
    __shared__ float sh_snew;

    if (tid < nk) {
        int k = tid, i1, i2;
        if (INSIDE) {
            i1 = coff(k) + pos;
            i2 = coff(lv - k - 1) + pos + k + 1;
        } else {
            if (k < pos) { i1 = coff(lv + k + 1) + pos - k - 1; i2 = coff(k) + pos - k - 1; }
            else         { int j = k - pos; i1 = coff(lv + j + 1) + pos; i2 = coff(j) + pos + lv + 1; }
        }
        o1s[k] = (b * NCELL + i1) * 800;        // hA
        o2s[k] = (b * NCELL + i2) * 800 + 400;  // hB
        c1s[k] = (b * NCELL + i1) * 400;        // hCb (score)
        h2s[k] = (b * NCELL + i2) * 400;        // hHin (score)
        q1s[k] = (b * NCELL + i1) * STR;
        q2s[k] = (b * NCELL + i2) * STR;
    }
    for (int f = tid; f < DD; f += 256) bsh[f] = bias[f];
    __syncthreads();

    // Phase A: scores sb_k = dot(hCb[i1], hHin[i2]) + s1 + s2
    {
        const int g = tid >> 4, gl = tid & 15;
        for (int k = g; k < nk; k += 16) {
            const unsigned short* v1 = hCb + c1s[k];
            const unsigned short* v2 = hHin + h2s[k];
            float acc = 0.f;
            for (int j = gl * 4; j < 400; j += 64) {
                ushort4 a = *(const ushort4*)(v1 + j);
                ushort4 c = *(const ushort4*)(v2 + j);
                acc += bf2f(a.x) * bf2f(c.x) + bf2f(a.y) * bf2f(c.y)
                     + bf2f(a.z) * bf2f(c.z) + bf2f(a.w) * bf2f(c.w);
            }
            acc += __shfl_xor(acc, 8);
            acc += __shfl_xor(acc, 4);
            acc += __shfl_xor(acc, 2);
            acc += __shfl_xor(acc, 1);
            if (gl == 0)
                sbs[k] = acc + obuf[q1s[k] + sA] + obuf[q2s[k] + DD];
        }
    }
    __syncthreads();

    // softmax (wave 0), also s_new = sum p*sb
    if (tid < 64) {
        float v = (tid < nk) ? sbs[tid] : -INFINITY;
        float m = v;
        #pragma unroll
        for (int o = 32; o; o >>= 1) m = fmaxf(m, __shfl_xor(m, o));
        float e = (tid < nk) ? __expf(v - m) : 0.f;
        float s = e;
        #pragma unroll
        for (int o = 32; o; o >>= 1) s += __shfl_xor(s, o);
        float p = e / s;
        if (tid < nk) ps[tid] = p;
        float pv = (tid < nk) ? p * v : 0.f;
        #pragma unroll
        for (int o = 32; o; o >>= 1) pv += __shfl_xor(pv, o);
        if (tid == 0) sh_snew = pv;
    }
    __syncthreads();

    // Phase B: h_new = sum_k p_k * relu(hA[i1] + hB[i2] + bias)
    if (tid < 200) {
        const int f = 2 * tid;
        const float bf0 = bsh[f], bf1 = bsh[f + 1];
        float ax = 0.f, ay = 0.f;
        #pragma unroll 4
        for (int k = 0; k < nk; ++k) {
            ushort2 a = *(const ushort2*)(hAB + o1s[k] + f);
            ushort2 c = *(const ushort2*)(hAB + o2s[k] + f);
            float p = ps[k];
            ax += p * fmaxf(bf2f(a.x) + bf2f(c.x) + bf0, 0.f);
            ay += p * fmaxf(bf2f(a.y) + bf2f(c.y) + bf1, 0.f);
        }
        hnew[f] = ax; hnew[f + 1] = ay;
    }
    __syncthreads();

    // norm
    float ss = 0.f;
    for (int f = tid; f < DD; f += 256) { float v = hnew[f]; ss += v * v; }
    #pragma unroll
    for (int o = 32; o; o >>= 1) ss += __shfl_xor(ss, o);
    if ((tid & 63) == 0) red[tid >> 6] = ss;
    __syncthreads();
    float rinv = 1.f / (sqrtf(red[0] + red[1] + red[2] + red[3]) + 1e-8f);

    const int hoff = INSIDE ? 0 : (DD + 1);
    const int soff = INSIDE ? DD : (STR - 1);
    size_t orow = ((size_t)(b * NCELL) + cell) * STR;
    size_t hrow = ((size_t)(b * NCELL) + cell) * 400;
    for (int f = tid; f < DD; f += 256) {
        float v = hnew[f] * rinv;
        obuf[orow + hoff + f] = v;
        hHw[hrow + f] = f2bf(v);
    }
    if (tid == 0) obuf[orow + soff] = sh_snew;
}

// ---- root: hAB[root][0:400)=u@Wout_top, hCb[root]=u@Sout, obuf h_out/s_out --
__global__ __launch_bounds__(256)
void root_trans(const float* __restrict__ rooth, const float* __restrict__ Wout,
                const float* __restrict__ Sout,
                unsigned short* __restrict__ hAB, unsigned short* __restrict__ hCb,
                float* obuf)
{
    const int tid = threadIdx.x;
    __shared__ float u[DD];
    __shared__ float red[4];
    __shared__ float part[4][64];
    float ss = 0.f;
    for (int f = tid; f < DD; f += 256) { float v = rooth[f]; ss += v * v; }
    #pragma unroll
    for (int o = 32; o; o >>= 1) ss += __shfl_xor(ss, o);
    if ((tid & 63) == 0) red[tid >> 6] = ss;
    __syncthreads();
    float rinv = 1.f / (sqrtf(red[0] + red[1] + red[2] + red[3]) + 1e-8f);
    for (int f = tid; f < DD; f += 256) u[f] = rooth[f] * rinv;
    __syncthreads();

    const int w = tid >> 6, lane = tid & 63;
    const int n = blockIdx.x * 64 + lane;
    float acc = 0.f;
    if (n < 800) {
        int mat = n / DD;
        const float* Mp = mat ? Sout : Wout;
        int c = n - mat * DD;
        #pragma unroll 4
        for (int k = w * 100; k < w * 100 + 100; ++k) acc += u[k] * Mp[(size_t)k * DD + c];
    }
    part[w][lane] = acc;
    if (w == 1 && n < 400) {
        for (int b = 0; b < 32; ++b)
            obuf[((size_t)b * NCELL + NCELL - 1) * STR + DD + 1 + n] = u[n];
    }
    if (w == 2 && blockIdx.x == 0 && lane < 32)
        obuf[((size_t)lane * NCELL + NCELL - 1) * STR + (STR - 1)] = 0.f;
    __syncthreads();
    if (w == 0 && n < 800) {
        float v = part[0][lane] + part[1][lane] + part[2][lane] + part[3][lane];
        unsigned short bv = f2bf(v);
        if (n < 400) {
            for (int b = 0; b < 32; ++b)
                hAB[((size_t)b * NCELL + NCELL - 1) * 800 + n] = bv;
        } else {
            for (int b = 0; b < 32; ++b)
                hCb[((size_t)b * NCELL + NCELL - 1) * 400 + (n - 400)] = bv;
        }
    }
}

extern "C" void kernel_launch(void* const* d_in, const int* in_sizes, int n_in,
                              void* d_out, int out_size, void* d_ws, size_t ws_size,
                              hipStream_t stream)
{
    const float* x     = (const float*)d_in[0];
    const float* Wl    = (const float*)d_in[1];
    const float* blf   = (const float*)d_in[2];
    const float* Win   = (const float*)d_in[3];
    const float* bin   = (const float*)d_in[4];
    const float* Sin   = (const float*)d_in[5];
    const float* Wout  = (const float*)d_in[6];
    const float* bout  = (const float*)d_in[7];
    const float* Sout  = (const float*)d_in[8];
    const float* rooth = (const float*)d_in[9];

    float* obuf = (float*)d_out;
    const size_t CELLS = (size_t)32 * NCELL;
    unsigned short* hAB   = (unsigned short*)d_ws;          // 42 MB
    unsigned short* hCb   = hAB   + CELLS * 800;            // 21 MB
    unsigned short* hHin  = hCb   + CELLS * 400;            // 21 MB
    unsigned short* hHout = hHin  + CELLS * 400;            // 21 MB
    unsigned short* WinT  = hHout + CELLS * 400;            // 0.96 MB
    unsigned short* WoutT = WinT  + (size_t)1200 * 400;     // 0.96 MB
    unsigned short* WlT   = WoutT + (size_t)1200 * 400;     // 0.82 MB
    float* leafS = (float*)(WlT + (size_t)400 * 1024);      // 2 MB fp32

    prep_weights<<<2800, 256, 0, stream>>>(Win, Sin, Wout, Sout, Wl, WinT, WoutT, WlT);

    // leaf projection (MFMA): relu(x @ W_leaf + b) -> leafS
    mleaf<<<dim3(20, 4), 256, 0, stream>>>(x, WlT, blf, leafS);
    unit_leaf<<<320, 256, 0, stream>>>(obuf, leafS, hHin);

    // inside pass
    for (int lv = 0; lv < TLEN; ++lv) {
        int L = TLEN - lv;
        int cb = coff(lv);
        if (lv > 0)
            compose_kernel<1><<<L * 32, 256, 0, stream>>>(lv, obuf, hAB, hCb,
                                                          hHin, hHin, bin);
        if (lv < TLEN - 1) {
            int M = L * 32;
            dim3 g((M + 63) / 64, 10);   // N=1200
            mgemm<<<g, 256, 0, stream>>>(hHin, WinT, hAB, hCb, M, 1200, L, cb, 0, 800);
        }
    }

    // prep: hAB[:, 400:800) = h_in @ W_out_bot for ALL cells (parallel GEMM)
    mgemm<<<dim3(410, 4), 256, 0, stream>>>(hHin, WoutT + (size_t)800 * 400,
                                            hAB, hCb, 32 * NCELL, 400, NCELL,
                                            0, 400, 400);
    root_trans<<<13, 256, 0, stream>>>(rooth, Wout, Sout, hAB, hCb, obuf);

    // outside pass
    for (int lv = TLEN - 2; lv >= 0; --lv) {
        int L = TLEN - lv;
        int cb = coff(lv);
        compose_kernel<0><<<L * 32, 256, 0, stream>>>(lv, obuf, hAB, hCb,
                                                      hHin, hHout, bout);
        if (lv > 0) {
            int M = L * 32;
            dim3 g((M + 63) / 64, 7);    // N=800
            mgemm<<<g, 256, 0, stream>>>(hHout, WoutT, hAB, hCb, M, 800, L, cb, 0, 400);
        }
    }
}

// Round 15
// 1980.220 us; speedup vs baseline: 5.5675x; 1.0297x over previous
//
#include <hip/hip_runtime.h>
#include <hip/hip_bf16.h>
#include <math.h>

// DIORA forward, MI355X. B=32, T=40, D_IN=1024, D=400.
// R14 champion (per-level launches, double-buffered BK=32 mgemm, N=1200
// inside, parallel prep GEMM, merged root) + wide-load compose:
//   phase A 16B score loads, phase B 8B loads (100 threads x 4 f's).
// ws (bf16 unless noted):
//   hAB  (32,820,800)  [hA | hB]   hCb (32,820,400) score transform
//   hHin (32,820,400)  h_in bf16   hHout(32,820,400) h_out bf16
//   WinT (1200,400) K-major [Win_top^T|Win_bot^T|Sin^T]
//   WoutT(1200,400) K-major [Wout_top^T|Sout^T|Wout_bot^T]
//   WlT  (400,1024) K-major W_leaf^T; leafS(1280,400) fp32
// obuf (32,820,802) fp32 = d_out: [h_in 400 | s_in 1 | h_out 400 | s_out 1]

#define TLEN 40
#define DD 400
#define NCELL 820
#define STR 802

typedef short bf16x8 __attribute__((ext_vector_type(8)));
typedef float f32x4 __attribute__((ext_vector_type(4)));

__host__ __device__ __forceinline__ int coff(int l) { return l * TLEN - (l * (l - 1)) / 2; }
__device__ __forceinline__ float bf2f(unsigned short u) {
    return __uint_as_float(((unsigned)u) << 16);
}
__device__ __forceinline__ unsigned short f2bf(float v) {
    __hip_bfloat16 h = __float2bfloat16(v);
    return *reinterpret_cast<unsigned short*>(&h);
}

// ---------------- weight prep: bf16 K-major transposed copies ----------------
__global__ __launch_bounds__(256)
void prep_weights(const float* __restrict__ Win, const float* __restrict__ Sin,
                  const float* __restrict__ Wout, const float* __restrict__ Sout,
                  const float* __restrict__ Wl,
                  unsigned short* __restrict__ WinT, unsigned short* __restrict__ WoutT,
                  unsigned short* __restrict__ WlT)
{
    int n = blockIdx.x;                 // 0..2799
    if (n < 2400) {
        const float* src; int col; unsigned short* dst;
        if (n < 1200) {
            dst = WinT + (size_t)n * 400;
            if (n < 400)      { src = Win;             col = n; }
            else if (n < 800) { src = Win + 400 * 400; col = n - 400; }
            else              { src = Sin;             col = n - 800; }
        } else {
            int m = n - 1200;
            dst = WoutT + (size_t)m * 400;
            if (m < 400)      { src = Wout;             col = m; }
            else if (m < 800) { src = Sout;             col = m - 400; }
            else              { src = Wout + 400 * 400; col = m - 800; }
        }
        for (int k = threadIdx.x; k < 400; k += 256)
            dst[k] = f2bf(src[(size_t)k * 400 + col]);
    } else {
        int m = n - 2400;               // 0..399
        unsigned short* dst = WlT + (size_t)m * 1024;
        for (int k = threadIdx.x; k < 1024; k += 256)
            dst[k] = f2bf(Wl[(size_t)k * 400 + m]);
    }
}

// ------- bf16 MFMA GEMM: 64x128 tile, BK=32, K=400, double-buffered LDS ------
__global__ __launch_bounds__(256)
void mgemm(const unsigned short* __restrict__ A, const unsigned short* __restrict__ WT,
           unsigned short* __restrict__ Cb, unsigned short* __restrict__ Cc,
           int M, int N, int L, int cb, int co_b, int nsplit)
{
    __shared__ unsigned short As[2][64][40];
    __shared__ unsigned short Bs[2][128][40];
    const int tid = threadIdx.x;
    const int bm = blockIdx.x, bn = blockIdx.y;
    const int w = tid >> 6, lane = tid & 63;
    const int l15 = lane & 15, kb = (lane >> 4) * 8;

    const int ar = tid >> 2, ach = (tid & 3) * 8;
    const int rg = bm * 64 + ar;
    const unsigned short* Ap = nullptr;
    if (rg < M) { int b = rg / L, p = rg - b * L;
                  Ap = A + ((size_t)(b * NCELL) + cb + p) * 400; }

    const int bcol = tid & 127, bh = (tid >> 7) * 16;
    const int ng = bn * 128 + bcol;
    const unsigned short* Bp = (ng < N) ? WT + (size_t)ng * 400 : nullptr;

    f32x4 acc[4][2];
    #pragma unroll
    for (int r = 0; r < 4; ++r)
        #pragma unroll
        for (int c = 0; c < 2; ++c) { f32x4 z = {0.f, 0.f, 0.f, 0.f}; acc[r][c] = z; }

    // prologue: stage k0=0 into buffer 0
    {
        int4 av = {0, 0, 0, 0};
        if (Ap && ach < 400) av = *(const int4*)(Ap + ach);
        int4 bv0 = {0, 0, 0, 0}, bv1 = {0, 0, 0, 0};
        if (Bp && bh < 400) {
            bv0 = *(const int4*)(Bp + bh);
            bv1 = *(const int4*)(Bp + bh + 8);
        }
        *(int4*)&As[0][ar][ach] = av;
        *(int4*)&Bs[0][bcol][bh] = bv0;
        *(int4*)&Bs[0][bcol][bh + 8] = bv1;
    }
    __syncthreads();

    int cur = 0;
    for (int k0 = 0; k0 < 400; k0 += 32) {
        const int nxt = k0 + 32;
        int4 av = {0, 0, 0, 0}, bv0 = {0, 0, 0, 0}, bv1 = {0, 0, 0, 0};
        if (nxt < 400) {
            if (Ap && (nxt + ach) < 400) av = *(const int4*)(Ap + nxt + ach);
            if (Bp && (nxt + bh) < 400) {
                bv0 = *(const int4*)(Bp + nxt + bh);
                bv1 = *(const int4*)(Bp + nxt + bh + 8);
            }
        }

        bf16x8 af[4], bf[2];
        #pragma unroll
        for (int r = 0; r < 4; ++r) af[r] = *(const bf16x8*)&As[cur][r * 16 + l15][kb];
        #pragma unroll
        for (int c = 0; c < 2; ++c) bf[c] = *(const bf16x8*)&Bs[cur][w * 32 + c * 16 + l15][kb];
        #pragma unroll
        for (int r = 0; r < 4; ++r)
            #pragma unroll
            for (int c = 0; c < 2; ++c)
                acc[r][c] = __builtin_amdgcn_mfma_f32_16x16x32_bf16(af[r], bf[c], acc[r][c], 0, 0, 0);

        if (nxt < 400) {
            *(int4*)&As[cur ^ 1][ar][ach] = av;
            *(int4*)&Bs[cur ^ 1][bcol][bh] = bv0;
            *(int4*)&Bs[cur ^ 1][bcol][bh + 8] = bv1;
            __syncthreads();
        }
        cur ^= 1;
    }

    const int rowb = (lane >> 4) * 4;
    #pragma unroll
    for (int r = 0; r < 4; ++r) {
        #pragma unroll
        for (int c = 0; c < 2; ++c) {
            int gcol = bn * 128 + w * 32 + c * 16 + l15;
            if (gcol >= N) continue;
            #pragma unroll
            for (int reg = 0; reg < 4; ++reg) {
                int rr = bm * 64 + r * 16 + rowb + reg;
                if (rr >= M) continue;
                int b = rr / L, p = rr - b * L;
                size_t cell = (size_t)(b * NCELL) + cb + p;
                unsigned short v = f2bf(acc[r][c][reg]);
                if (gcol < nsplit) Cb[cell * 800 + co_b + gcol] = v;
                else               Cc[cell * 400 + (gcol - nsplit)] = v;
            }
        }
    }
}

// ---------------- leaf MFMA GEMM: x(fp32,K=1024) @ WlT -> leafS fp32 ---------
__global__ __launch_bounds__(256)
void mleaf(const float* __restrict__ x, const unsigned short* __restrict__ WlT,
           const float* __restrict__ bias, float* __restrict__ leafS)
{
    __shared__ unsigned short As[64][40];
    __shared__ unsigned short Bs[128][40];
    const int tid = threadIdx.x;
    const int bm = blockIdx.x, bn = blockIdx.y;
    const int w = tid >> 6, lane = tid & 63;
    const int l15 = lane & 15, kb = (lane >> 4) * 8;

    const int ar = tid >> 2, ach = (tid & 3) * 8;
    const float* Ap = x + (size_t)(bm * 64 + ar) * 1024;

    const int bcol = tid & 127, bh = (tid >> 7) * 16;
    const int ng = bn * 128 + bcol;
    const unsigned short* Bp = (ng < 400) ? WlT + (size_t)ng * 1024 : nullptr;

    f32x4 acc[4][2];
    #pragma unroll
    for (int r = 0; r < 4; ++r)
        #pragma unroll
        for (int c = 0; c < 2; ++c) { f32x4 z = {0.f, 0.f, 0.f, 0.f}; acc[r][c] = z; }

    for (int k0 = 0; k0 < 1024; k0 += 32) {
        float4 p0 = *(const float4*)(Ap + k0 + ach);
        float4 p1 = *(const float4*)(Ap + k0 + ach + 4);
        unsigned short av[8];
        av[0] = f2bf(p0.x); av[1] = f2bf(p0.y); av[2] = f2bf(p0.z); av[3] = f2bf(p0.w);
        av[4] = f2bf(p1.x); av[5] = f2bf(p1.y); av[6] = f2bf(p1.z); av[7] = f2bf(p1.w);
        int4 bv0 = {0, 0, 0, 0}, bv1 = {0, 0, 0, 0};
        if (Bp) {
            bv0 = *(const int4*)(Bp + k0 + bh);
            bv1 = *(const int4*)(Bp + k0 + bh + 8);
        }
        __syncthreads();
        *(int4*)&As[ar][ach] = *(const int4*)av;
        *(int4*)&Bs[bcol][bh] = bv0;
        *(int4*)&Bs[bcol][bh + 8] = bv1;
        __syncthreads();

        bf16x8 af[4], bf[2];
        #pragma unroll
        for (int r = 0; r < 4; ++r) af[r] = *(const bf16x8*)&As[r * 16 + l15][kb];
        #pragma unroll
        for (int c = 0; c < 2; ++c) bf[c] = *(const bf16x8*)&Bs[w * 32 + c * 16 + l15][kb];
        #pragma unroll
        for (int r = 0; r < 4; ++r)
            #pragma unroll
            for (int c = 0; c < 2; ++c)
                acc[r][c] = __builtin_amdgcn_mfma_f32_16x16x32_bf16(af[r], bf[c], acc[r][c], 0, 0, 0);
    }

    const int rowb = (lane >> 4) * 4;
    #pragma unroll
    for (int r = 0; r < 4; ++r) {
        #pragma unroll
        for (int c = 0; c < 2; ++c) {
            int gcol = bn * 128 + w * 32 + c * 16 + l15;
            if (gcol >= 400) continue;
            float bv = bias[gcol];
            #pragma unroll
            for (int reg = 0; reg < 4; ++reg) {
                int rr = bm * 64 + r * 16 + rowb + reg;
                leafS[(size_t)rr * 400 + gcol] = fmaxf(acc[r][c][reg] + bv, 0.f);
            }
        }
    }
}

// ---------------- normalize leaf rows ----------
__global__ __launch_bounds__(256)
void unit_leaf(float* obuf, const float* __restrict__ leafS, unsigned short* __restrict__ hHin)
{
    int w = threadIdx.x >> 6, lane = threadIdx.x & 63;
    int r = blockIdx.x * 4 + w;                 // 0..1279 = (b, pos)
    int b = r / TLEN, pos = r - b * TLEN;
    const float* t = leafS + (size_t)r * 400;
    float ss = 0.f;
    for (int f = lane; f < DD; f += 64) { float v = t[f]; ss += v * v; }
    #pragma unroll
    for (int o = 32; o; o >>= 1) ss += __shfl_xor(ss, o);
    float rinv = 1.f / (sqrtf(ss) + 1e-8f);
    size_t orow = ((size_t)b * NCELL + pos) * STR;
    size_t hrow = ((size_t)b * NCELL + pos) * 400;
    for (int f = lane; f < DD; f += 64) {
        float v = t[f] * rinv;
        obuf[orow + f] = v;
        hHin[hrow + f] = f2bf(v);
    }
    if (lane == 0) obuf[orow + DD] = 0.f;       // s_in(leaf)=0
}

// ---------------- per-level compose (wide loads) ----------------
template<int INSIDE>
__global__ __launch_bounds__(256)
void compose_kernel(int lv, float* obuf, const unsigned short* __restrict__ hAB,
                    const unsigned short* __restrict__ hCb,
                    const unsigned short* __restrict__ hHin,
                    unsigned short* __restrict__ hHw,
                    const float* __restrict__ bias)
{
    const int nk  = INSIDE ? lv : (TLEN - 1 - lv);
    const int b   = blockIdx.x & 31;
    const int pos = blockIdx.x >> 5;
    const int cell = coff(lv) + pos;
    const int tid = threadIdx.x;
    const int sA  = INSIDE ? DD : (STR - 1);  // s-term offset for i1 in obuf

    __shared__ int   o1s[TLEN], o2s[TLEN], c1s[TLEN], h2s[TLEN], q1s[TLEN], q2s[TLEN];
    __shared__ float sbs[TLEN], ps[TLEN];
    __shared__ float bsh[DD];
    __shared__ float hnew[DD];
    __shared__ float red[4];
    __shared__ float sh_snew;

    if (tid < nk) {
        int k = tid, i1, i2;
        if (INSIDE) {
            i1 = coff(k) + pos;
            i2 = coff(lv - k - 1) + pos + k + 1;
        } else {
            if (k < pos) { i1 = coff(lv + k + 1) + pos - k - 1; i2 = coff(k) + pos - k - 1; }
            else         { int j = k - pos; i1 = coff(lv + j + 1) + pos; i2 = coff(j) + pos + lv + 1; }
        }
        o1s[k] = (b * NCELL + i1) * 800;        // hA
        o2s[k] = (b * NCELL + i2) * 800 + 400;  // hB
        c1s[k] = (b * NCELL + i1) * 400;        // hCb (score)
        h2s[k] = (b * NCELL + i2) * 400;        // hHin (score)
        q1s[k] = (b * NCELL + i1) * STR;
        q2s[k] = (b * NCELL + i2) * STR;
    }
    for (int f = tid; f < DD; f += 256) bsh[f] = bias[f];
    __syncthreads();

    // Phase A: scores sb_k = dot(hCb[i1], hHin[i2]) + s1 + s2  (16B loads)
    {
        const int g = tid >> 4, gl = tid & 15;
        for (int k = g; k < nk; k += 16) {
            const unsigned short* v1 = hCb + c1s[k];
            const unsigned short* v2 = hHin + h2s[k];
            float acc = 0.f;
            for (int j = gl * 8; j < 400; j += 128) {
                int4 ai = *(const int4*)(v1 + j);
                int4 ci = *(const int4*)(v2 + j);
                const unsigned short* a = (const unsigned short*)&ai;
                const unsigned short* c = (const unsigned short*)&ci;
                #pragma unroll
                for (int e = 0; e < 8; ++e) acc += bf2f(a[e]) * bf2f(c[e]);
            }
            acc += __shfl_xor(acc, 8);
            acc += __shfl_xor(acc, 4);
            acc += __shfl_xor(acc, 2);
            acc += __shfl_xor(acc, 1);
            if (gl == 0)
                sbs[k] = acc + obuf[q1s[k] + sA] + obuf[q2s[k] + DD];
        }
    }
    __syncthreads();

    // softmax (wave 0), also s_new = sum p*sb
    if (tid < 64) {
        float v = (tid < nk) ? sbs[tid] : -INFINITY;
        float m = v;
        #pragma unroll
        for (int o = 32; o; o >>= 1) m = fmaxf(m, __shfl_xor(m, o));
        float e = (tid < nk) ? __expf(v - m) : 0.f;
        float s = e;
        #pragma unroll
        for (int o = 32; o; o >>= 1) s += __shfl_xor(s, o);
        float p = e / s;
        if (tid < nk) ps[tid] = p;
        float pv = (tid < nk) ? p * v : 0.f;
        #pragma unroll
        for (int o = 32; o; o >>= 1) pv += __shfl_xor(pv, o);
        if (tid == 0) sh_snew = pv;
    }
    __syncthreads();

    // Phase B: h_new = sum_k p_k * relu(hA[i1] + hB[i2] + bias)  (8B loads,
    // 100 threads x 4 f's, static per-thread f-ownership)
    if (tid < 100) {
        const int f = 4 * tid;
        float bf0 = bsh[f], bf1 = bsh[f + 1], bf2 = bsh[f + 2], bf3 = bsh[f + 3];
        float a0 = 0.f, a1 = 0.f, a2 = 0.f, a3 = 0.f;
        #pragma unroll 4
        for (int k = 0; k < nk; ++k) {
            ushort4 a = *(const ushort4*)(hAB + o1s[k] + f);
            ushort4 c = *(const ushort4*)(hAB + o2s[k] + f);
            float p = ps[k];
            a0 += p * fmaxf(bf2f(a.x) + bf2f(c.x) + bf0, 0.f);
            a1 += p * fmaxf(bf2f(a.y) + bf2f(c.y) + bf1, 0.f);
            a2 += p * fmaxf(bf2f(a.z) + bf2f(c.z) + bf2, 0.f);
            a3 += p * fmaxf(bf2f(a.w) + bf2f(c.w) + bf3, 0.f);
        }
        hnew[f] = a0; hnew[f + 1] = a1; hnew[f + 2] = a2; hnew[f + 3] = a3;
    }
    __syncthreads();

    // norm
    float ss = 0.f;
    for (int f = tid; f < DD; f += 256) { float v = hnew[f]; ss += v * v; }
    #pragma unroll
    for (int o = 32; o; o >>= 1) ss += __shfl_xor(ss, o);
    if ((tid & 63) == 0) red[tid >> 6] = ss;
    __syncthreads();
    float rinv = 1.f / (sqrtf(red[0] + red[1] + red[2] + red[3]) + 1e-8f);

    const int hoff = INSIDE ? 0 : (DD + 1);
    const int soff = INSIDE ? DD : (STR - 1);
    size_t orow = ((size_t)(b * NCELL) + cell) * STR;
    size_t hrow = ((size_t)(b * NCELL) + cell) * 400;
    for (int f = tid; f < DD; f += 256) {
        float v = hnew[f] * rinv;
        obuf[orow + hoff + f] = v;
        hHw[hrow + f] = f2bf(v);
    }
    if (tid == 0) obuf[orow + soff] = sh_snew;
}

// ---- root: hAB[root][0:400)=u@Wout_top, hCb[root]=u@Sout, obuf h_out/s_out --
__global__ __launch_bounds__(256)
void root_trans(const float* __restrict__ rooth, const float* __restrict__ Wout,
                const float* __restrict__ Sout,
                unsigned short* __restrict__ hAB, unsigned short* __restrict__ hCb,
                float* obuf)
{
    const int tid = threadIdx.x;
    __shared__ float u[DD];
    __shared__ float red[4];
    __shared__ float part[4][64];
    float ss = 0.f;
    for (int f = tid; f < DD; f += 256) { float v = rooth[f]; ss += v * v; }
    #pragma unroll
    for (int o = 32; o; o >>= 1) ss += __shfl_xor(ss, o);
    if ((tid & 63) == 0) red[tid >> 6] = ss;
    __syncthreads();
    float rinv = 1.f / (sqrtf(red[0] + red[1] + red[2] + red[3]) + 1e-8f);
    for (int f = tid; f < DD; f += 256) u[f] = rooth[f] * rinv;
    __syncthreads();

    const int w = tid >> 6, lane = tid & 63;
    const int n = blockIdx.x * 64 + lane;
    float acc = 0.f;
    if (n < 800) {
        int mat = n / DD;
        const float* Mp = mat ? Sout : Wout;
        int c = n - mat * DD;
        #pragma unroll 4
        for (int k = w * 100; k < w * 100 + 100; ++k) acc += u[k] * Mp[(size_t)k * DD + c];
    }
    part[w][lane] = acc;
    if (w == 1 && n < 400) {
        for (int b = 0; b < 32; ++b)
            obuf[((size_t)b * NCELL + NCELL - 1) * STR + DD + 1 + n] = u[n];
    }
    if (w == 2 && blockIdx.x == 0 && lane < 32)
        obuf[((size_t)lane * NCELL + NCELL - 1) * STR + (STR - 1)] = 0.f;
    __syncthreads();
    if (w == 0 && n < 800) {
        float v = part[0][lane] + part[1][lane] + part[2][lane] + part[3][lane];
        unsigned short bv = f2bf(v);
        if (n < 400) {
            for (int b = 0; b < 32; ++b)
                hAB[((size_t)b * NCELL + NCELL - 1) * 800 + n] = bv;
        } else {
            for (int b = 0; b < 32; ++b)
                hCb[((size_t)b * NCELL + NCELL - 1) * 400 + (n - 400)] = bv;
        }
    }
}

extern "C" void kernel_launch(void* const* d_in, const int* in_sizes, int n_in,
                              void* d_out, int out_size, void* d_ws, size_t ws_size,
                              hipStream_t stream)
{
    const float* x     = (const float*)d_in[0];
    const float* Wl    = (const float*)d_in[1];
    const float* blf   = (const float*)d_in[2];
    const float* Win   = (const float*)d_in[3];
    const float* bin   = (const float*)d_in[4];
    const float* Sin   = (const float*)d_in[5];
    const float* Wout  = (const float*)d_in[6];
    const float* bout  = (const float*)d_in[7];
    const float* Sout  = (const float*)d_in[8];
    const float* rooth = (const float*)d_in[9];

    float* obuf = (float*)d_out;
    const size_t CELLS = (size_t)32 * NCELL;
    unsigned short* hAB   = (unsigned short*)d_ws;          // 42 MB
    unsigned short* hCb   = hAB   + CELLS * 800;            // 21 MB
    unsigned short* hHin  = hCb   + CELLS * 400;            // 21 MB
    unsigned short* hHout = hHin  + CELLS * 400;            // 21 MB
    unsigned short* WinT  = hHout + CELLS * 400;            // 0.96 MB
    unsigned short* WoutT = WinT  + (size_t)1200 * 400;     // 0.96 MB
    unsigned short* WlT   = WoutT + (size_t)1200 * 400;     // 0.82 MB
    float* leafS = (float*)(WlT + (size_t)400 * 1024);      // 2 MB fp32

    prep_weights<<<2800, 256, 0, stream>>>(Win, Sin, Wout, Sout, Wl, WinT, WoutT, WlT);

    // leaf projection (MFMA): relu(x @ W_leaf + b) -> leafS
    mleaf<<<dim3(20, 4), 256, 0, stream>>>(x, WlT, blf, leafS);
    unit_leaf<<<320, 256, 0, stream>>>(obuf, leafS, hHin);

    // inside pass
    for (int lv = 0; lv < TLEN; ++lv) {
        int L = TLEN - lv;
        int cb = coff(lv);
        if (lv > 0)
            compose_kernel<1><<<L * 32, 256, 0, stream>>>(lv, obuf, hAB, hCb,
                                                          hHin, hHin, bin);
        if (lv < TLEN - 1) {
            int M = L * 32;
            dim3 g((M + 63) / 64, 10);   // N=1200
            mgemm<<<g, 256, 0, stream>>>(hHin, WinT, hAB, hCb, M, 1200, L, cb, 0, 800);
        }
    }

    // prep: hAB[:, 400:800) = h_in @ W_out_bot for ALL cells (parallel GEMM)
    mgemm<<<dim3(410, 4), 256, 0, stream>>>(hHin, WoutT + (size_t)800 * 400,
                                            hAB, hCb, 32 * NCELL, 400, NCELL,
                                            0, 400, 400);
    root_trans<<<13, 256, 0, stream>>>(rooth, Wout, Sout, hAB, hCb, obuf);

    // outside pass
    for (int lv = TLEN - 2; lv >= 0; --lv) {
        int L = TLEN - lv;
        int cb = coff(lv);
        compose_kernel<0><<<L * 32, 256, 0, stream>>>(lv, obuf, hAB, hCb,
                                                      hHin, hHout, bout);
        if (lv > 0) {
            int M = L * 32;
            dim3 g((M + 63) / 64, 7);    // N=800
            mgemm<<<g, 256, 0, stream>>>(hHout, WoutT, hAB, hCb, M, 800, L, cb, 0, 400);
        }
    }
}

// Round 16
// 1919.608 us; speedup vs baseline: 5.7433x; 1.0316x over previous
//
#include <hip/hip_runtime.h>
#include <hip/hip_bf16.h>
#include <math.h>

// DIORA forward, MI355X. B=32, T=40, D_IN=1024, D=400.
// R15 champion + compose ILP: phase A fully-unrolled 16B loads, phase B
// k-unroll 8 (deep load queue; compose is grid-starved latency-bound).
// ws (bf16 unless noted):
//   hAB  (32,820,800)  [hA | hB]   hCb (32,820,400) score transform
//   hHin (32,820,400)  h_in bf16   hHout(32,820,400) h_out bf16
//   WinT (1200,400) K-major [Win_top^T|Win_bot^T|Sin^T]
//   WoutT(1200,400) K-major [Wout_top^T|Sout^T|Wout_bot^T]
//   WlT  (400,1024) K-major W_leaf^T; leafS(1280,400) fp32
// obuf (32,820,802) fp32 = d_out: [h_in 400 | s_in 1 | h_out 400 | s_out 1]

#define TLEN 40
#define DD 400
#define NCELL 820
#define STR 802

typedef short bf16x8 __attribute__((ext_vector_type(8)));
typedef float f32x4 __attribute__((ext_vector_type(4)));

__host__ __device__ __forceinline__ int coff(int l) { return l * TLEN - (l * (l - 1)) / 2; }
__device__ __forceinline__ float bf2f(unsigned short u) {
    return __uint_as_float(((unsigned)u) << 16);
}
__device__ __forceinline__ unsigned short f2bf(float v) {
    __hip_bfloat16 h = __float2bfloat16(v);
    return *reinterpret_cast<unsigned short*>(&h);
}
__device__ __forceinline__ float dot8(int4 ai, int4 ci) {
    const unsigned short* a = (const unsigned short*)&ai;
    const unsigned short* c = (const unsigned short*)&ci;
    float s = 0.f;
    #pragma unroll
    for (int e = 0; e < 8; ++e) s += bf2f(a[e]) * bf2f(c[e]);
    return s;
}

// ---------------- weight prep: bf16 K-major transposed copies ----------------
__global__ __launch_bounds__(256)
void prep_weights(const float* __restrict__ Win, const float* __restrict__ Sin,
                  const float* __restrict__ Wout, const float* __restrict__ Sout,
                  const float* __restrict__ Wl,
                  unsigned short* __restrict__ WinT, unsigned short* __restrict__ WoutT,
                  unsigned short* __restrict__ WlT)
{
    int n = blockIdx.x;                 // 0..2799
    if (n < 2400) {
        const float* src; int col; unsigned short* dst;
        if (n < 1200) {
            dst = WinT + (size_t)n * 400;
            if (n < 400)      { src = Win;             col = n; }
            else if (n < 800) { src = Win + 400 * 400; col = n - 400; }
            else              { src = Sin;             col = n - 800; }
        } else {
            int m = n - 1200;
            dst = WoutT + (size_t)m * 400;
            if (m < 400)      { src = Wout;             col = m; }
            else if (m < 800) { src = Sout;             col = m - 400; }
            else              { src = Wout + 400 * 400; col = m - 800; }
        }
        for (int k = threadIdx.x; k < 400; k += 256)
            dst[k] = f2bf(src[(size_t)k * 400 + col]);
    } else {
        int m = n - 2400;               // 0..399
        unsigned short* dst = WlT + (size_t)m * 1024;
        for (int k = threadIdx.x; k < 1024; k += 256)
            dst[k] = f2bf(Wl[(size_t)k * 400 + m]);
    }
}

// ------- bf16 MFMA GEMM: 64x128 tile, BK=32, K=400, double-buffered LDS ------
__global__ __launch_bounds__(256)
void mgemm(const unsigned short* __restrict__ A, const unsigned short* __restrict__ WT,
           unsigned short* __restrict__ Cb, unsigned short* __restrict__ Cc,
           int M, int N, int L, int cb, int co_b, int nsplit)
{
    __shared__ unsigned short As[2][64][40];
    __shared__ unsigned short Bs[2][128][40];
    const int tid = threadIdx.x;
    const int bm = blockIdx.x, bn = blockIdx.y;
    const int w = tid >> 6, lane = tid & 63;
    const int l15 = lane & 15, kb = (lane >> 4) * 8;

    const int ar = tid >> 2, ach = (tid & 3) * 8;
    const int rg = bm * 64 + ar;
    const unsigned short* Ap = nullptr;
    if (rg < M) { int b = rg / L, p = rg - b * L;
                  Ap = A + ((size_t)(b * NCELL) + cb + p) * 400; }

    const int bcol = tid & 127, bh = (tid >> 7) * 16;
    const int ng = bn * 128 + bcol;
    const unsigned short* Bp = (ng < N) ? WT + (size_t)ng * 400 : nullptr;

    f32x4 acc[4][2];
    #pragma unroll
    for (int r = 0; r < 4; ++r)
        #pragma unroll
        for (int c = 0; c < 2; ++c) { f32x4 z = {0.f, 0.f, 0.f, 0.f}; acc[r][c] = z; }

    // prologue: stage k0=0 into buffer 0
    {
        int4 av = {0, 0, 0, 0};
        if (Ap && ach < 400) av = *(const int4*)(Ap + ach);
        int4 bv0 = {0, 0, 0, 0}, bv1 = {0, 0, 0, 0};
        if (Bp && bh < 400) {
            bv0 = *(const int4*)(Bp + bh);
            bv1 = *(const int4*)(Bp + bh + 8);
        }
        *(int4*)&As[0][ar][ach] = av;
        *(int4*)&Bs[0][bcol][bh] = bv0;
        *(int4*)&Bs[0][bcol][bh + 8] = bv1;
    }
    __syncthreads();

    int cur = 0;
    for (int k0 = 0; k0 < 400; k0 += 32) {
        const int nxt = k0 + 32;
        int4 av = {0, 0, 0, 0}, bv0 = {0, 0, 0, 0}, bv1 = {0, 0, 0, 0};
        if (nxt < 400) {
            if (Ap && (nxt + ach) < 400) av = *(const int4*)(Ap + nxt + ach);
            if (Bp && (nxt + bh) < 400) {
                bv0 = *(const int4*)(Bp + nxt + bh);
                bv1 = *(const int4*)(Bp + nxt + bh + 8);
            }
        }

        bf16x8 af[4], bf[2];
        #pragma unroll
        for (int r = 0; r < 4; ++r) af[r] = *(const bf16x8*)&As[cur][r * 16 + l15][kb];
        #pragma unroll
        for (int c = 0; c < 2; ++c) bf[c] = *(const bf16x8*)&Bs[cur][w * 32 + c * 16 + l15][kb];
        #pragma unroll
        for (int r = 0; r < 4; ++r)
            #pragma unroll
            for (int c = 0; c < 2; ++c)
                acc[r][c] = __builtin_amdgcn_mfma_f32_16x16x32_bf16(af[r], bf[c], acc[r][c], 0, 0, 0);

        if (nxt < 400) {
            *(int4*)&As[cur ^ 1][ar][ach] = av;
            *(int4*)&Bs[cur ^ 1][bcol][bh] = bv0;
            *(int4*)&Bs[cur ^ 1][bcol][bh + 8] = bv1;
            __syncthreads();
        }
        cur ^= 1;
    }

    const int rowb = (lane >> 4) * 4;
    #pragma unroll
    for (int r = 0; r < 4; ++r) {
        #pragma unroll
        for (int c = 0; c < 2; ++c) {
            int gcol = bn * 128 + w * 32 + c * 16 + l15;
            if (gcol >= N) continue;
            #pragma unroll
            for (int reg = 0; reg < 4; ++reg) {
                int rr = bm * 64 + r * 16 + rowb + reg;
                if (rr >= M) continue;
                int b = rr / L, p = rr - b * L;
                size_t cell = (size_t)(b * NCELL) + cb + p;
                unsigned short v = f2bf(acc[r][c][reg]);
                if (gcol < nsplit) Cb[cell * 800 + co_b + gcol] = v;
                else               Cc[cell * 400 + (gcol - nsplit)] = v;
            }
        }
    }
}

// ---------------- leaf MFMA GEMM: x(fp32,K=1024) @ WlT -> leafS fp32 ---------
__global__ __launch_bounds__(256)
void mleaf(const float* __restrict__ x, const unsigned short* __restrict__ WlT,
           const float* __restrict__ bias, float* __restrict__ leafS)
{
    __shared__ unsigned short As[64][40];
    __shared__ unsigned short Bs[128][40];
    const int tid = threadIdx.x;
    const int bm = blockIdx.x, bn = blockIdx.y;
    const int w = tid >> 6, lane = tid & 63;
    const int l15 = lane & 15, kb = (lane >> 4) * 8;

    const int ar = tid >> 2, ach = (tid & 3) * 8;
    const float* Ap = x + (size_t)(bm * 64 + ar) * 1024;

    const int bcol = tid & 127, bh = (tid >> 7) * 16;
    const int ng = bn * 128 + bcol;
    const unsigned short* Bp = (ng < 400) ? WlT + (size_t)ng * 1024 : nullptr;

    f32x4 acc[4][2];
    #pragma unroll
    for (int r = 0; r < 4; ++r)
        #pragma unroll
        for (int c = 0; c < 2; ++c) { f32x4 z = {0.f, 0.f, 0.f, 0.f}; acc[r][c] = z; }

    for (int k0 = 0; k0 < 1024; k0 += 32) {
        float4 p0 = *(const float4*)(Ap + k0 + ach);
        float4 p1 = *(const float4*)(Ap + k0 + ach + 4);
        unsigned short av[8];
        av[0] = f2bf(p0.x); av[1] = f2bf(p0.y); av[2] = f2bf(p0.z); av[3] = f2bf(p0.w);
        av[4] = f2bf(p1.x); av[5] = f2bf(p1.y); av[6] = f2bf(p1.z); av[7] = f2bf(p1.w);
        int4 bv0 = {0, 0, 0, 0}, bv1 = {0, 0, 0, 0};
        if (Bp) {
            bv0 = *(const int4*)(Bp + k0 + bh);
            bv1 = *(const int4*)(Bp + k0 + bh + 8);
        }
        __syncthreads();
        *(int4*)&As[ar][ach] = *(const int4*)av;
        *(int4*)&Bs[bcol][bh] = bv0;
        *(int4*)&Bs[bcol][bh + 8] = bv1;
        __syncthreads();

        bf16x8 af[4], bf[2];
        #pragma unroll
        for (int r = 0; r < 4; ++r) af[r] = *(const bf16x8*)&As[r * 16 + l15][kb];
        #pragma unroll
        for (int c = 0; c < 2; ++c) bf[c] = *(const bf16x8*)&Bs[w * 32 + c * 16 + l15][kb];
        #pragma unroll
        for (int r = 0; r < 4; ++r)
            #pragma unroll
            for (int c = 0; c < 2; ++c)
                acc[r][c] = __builtin_amdgcn_mfma_f32_16x16x32_bf16(af[r], bf[c], acc[r][c], 0, 0, 0);
    }

    const int rowb = (lane >> 4) * 4;
    #pragma unroll
    for (int r = 0; r < 4; ++r) {
        #pragma unroll
        for (int c = 0; c < 2; ++c) {
            int gcol = bn * 128 + w * 32 + c * 16 + l15;
            if (gcol >= 400) continue;
            float bv = bias[gcol];
            #pragma unroll
            for (int reg = 0; reg < 4; ++reg) {
                int rr = bm * 64 + r * 16 + rowb + reg;
                leafS[(size_t)rr * 400 + gcol] = fmaxf(acc[r][c][reg] + bv, 0.f);
            }
        }
    }
}

// ---------------- normalize leaf rows ----------
__global__ __launch_bounds__(256)
void unit_leaf(float* obuf, const float* __restrict__ leafS, unsigned short* __restrict__ hHin)
{
    int w = threadIdx.x >> 6, lane = threadIdx.x & 63;
    int r = blockIdx.x * 4 + w;                 // 0..1279 = (b, pos)
    int b = r / TLEN, pos = r - b * TLEN;
    const float* t = leafS + (size_t)r * 400;
    float ss = 0.f;
    for (int f = lane; f < DD; f += 64) { float v = t[f]; ss += v * v; }
    #pragma unroll
    for (int o = 32; o; o >>= 1) ss += __shfl_xor(ss, o);
    float rinv = 1.f / (sqrtf(ss) + 1e-8f);
    size_t orow = ((size_t)b * NCELL + pos) * STR;
    size_t hrow = ((size_t)b * NCELL + pos) * 400;
    for (int f = lane; f < DD; f += 64) {
        float v = t[f] * rinv;
        obuf[orow + f] = v;
        hHin[hrow + f] = f2bf(v);
    }
    if (lane == 0) obuf[orow + DD] = 0.f;       // s_in(leaf)=0
}

// ---------------- per-level compose (deep-ILP loads) ----------------
template<int INSIDE>
__global__ __launch_bounds__(256)
void compose_kernel(int lv, float* obuf, const unsigned short* __restrict__ hAB,
                    const unsigned short* __restrict__ hCb,
                    const unsigned short* __restrict__ hHin,
                    unsigned short* __restrict__ hHw,
                    const float* __restrict__ bias)
{
    const int nk  = INSIDE ? lv : (TLEN - 1 - lv);
    const int b   = blockIdx.x & 31;
    const int pos = blockIdx.x >> 5;
    const int cell = coff(lv) + pos;
    const int tid = threadIdx.x;
    const int sA  = INSIDE ? DD : (STR - 1);  // s-term offset for i1 in obuf

    __shared__ int   o1s[TLEN], o2s[TLEN], c1s[TLEN], h2s[TLEN], q1s[TLEN], q2s[TLEN];
    __shared__ float sbs[TLEN], ps[TLEN];
    __shared__ float bsh[DD];
    __shared__ float hnew[DD];
    __shared__ float red[4];
    __shared__ float sh_snew;

    if (tid < nk) {
        int k = tid, i1, i2;
        if (INSIDE) {
            i1 = coff(k) + pos;
            i2 = coff(lv - k - 1) + pos + k + 1;
        } else {
            if (k < pos) { i1 = coff(lv + k + 1) + pos - k - 1; i2 = coff(k) + pos - k - 1; }
            else         { int j = k - pos; i1 = coff(lv + j + 1) + pos; i2 = coff(j) + pos + lv + 1; }
        }
        o1s[k] = (b * NCELL + i1) * 800;        // hA
        o2s[k] = (b * NCELL + i2) * 800 + 400;  // hB
        c1s[k] = (b * NCELL + i1) * 400;        // hCb (score)
        h2s[k] = (b * NCELL + i2) * 400;        // hHin (score)
        q1s[k] = (b * NCELL + i1) * STR;
        q2s[k] = (b * NCELL + i2) * STR;
    }
    for (int f = tid; f < DD; f += 256) bsh[f] = bias[f];
    __syncthreads();

    // Phase A: scores sb_k = dot(hCb[i1], hHin[i2]) + s1 + s2
    // fully unrolled: 3 fixed 16B-load chunks + tail chunk for lanes 0-1
    {
        const int g = tid >> 4, gl = tid & 15;
        for (int k = g; k < nk; k += 16) {
            const unsigned short* v1 = hCb + c1s[k];
            const unsigned short* v2 = hHin + h2s[k];
            const int j0 = gl * 8;
            // issue all loads up front (independent)
            int4 a0 = *(const int4*)(v1 + j0);
            int4 a1 = *(const int4*)(v1 + j0 + 128);
            int4 a2 = *(const int4*)(v1 + j0 + 256);
            int4 c0 = *(const int4*)(v2 + j0);
            int4 c1 = *(const int4*)(v2 + j0 + 128);
            int4 c2 = *(const int4*)(v2 + j0 + 256);
            int4 a3 = {0,0,0,0}, c3 = {0,0,0,0};
            if (gl < 2) {                       // tail: elems 384..399
                a3 = *(const int4*)(v1 + 384 + j0);
                c3 = *(const int4*)(v2 + 384 + j0);
            }
            float acc = dot8(a0, c0) + dot8(a1, c1) + dot8(a2, c2);
            if (gl < 2) acc += dot8(a3, c3);
            acc += __shfl_xor(acc, 8);
            acc += __shfl_xor(acc, 4);
            acc += __shfl_xor(acc, 2);
            acc += __shfl_xor(acc, 1);
            if (gl == 0)
                sbs[k] = acc + obuf[q1s[k] + sA] + obuf[q2s[k] + DD];
        }
    }
    __syncthreads();

    // softmax (wave 0), also s_new = sum p*sb
    if (tid < 64) {
        float v = (tid < nk) ? sbs[tid] : -INFINITY;
        float m = v;
        #pragma unroll
        for (int o = 32; o; o >>= 1) m = fmaxf(m, __shfl_xor(m, o));
        float e = (tid < nk) ? __expf(v - m) : 0.f;
        float s = e;
        #pragma unroll
        for (int o = 32; o; o >>= 1) s += __shfl_xor(s, o);
        float p = e / s;
        if (tid < nk) ps[tid] = p;
        float pv = (tid < nk) ? p * v : 0.f;
        #pragma unroll
        for (int o = 32; o; o >>= 1) pv += __shfl_xor(pv, o);
        if (tid == 0) sh_snew = pv;
    }
    __syncthreads();

    // Phase B: h_new = sum_k p_k * relu(hA[i1] + hB[i2] + bias)
    // 100 threads x 4 f's, k-unroll 8 (16 independent 8B loads in flight)
    if (tid < 100) {
        const int f = 4 * tid;
        float bf0 = bsh[f], bf1 = bsh[f + 1], bf2 = bsh[f + 2], bf3 = bsh[f + 3];
        float a0 = 0.f, a1 = 0.f, a2 = 0.f, a3 = 0.f;
        #pragma unroll 8
        for (int k = 0; k < nk; ++k) {
            ushort4 a = *(const ushort4*)(hAB + o1s[k] + f);
            ushort4 c = *(const ushort4*)(hAB + o2s[k] + f);
            float p = ps[k];
            a0 += p * fmaxf(bf2f(a.x) + bf2f(c.x) + bf0, 0.f);
            a1 += p * fmaxf(bf2f(a.y) + bf2f(c.y) + bf1, 0.f);
            a2 += p * fmaxf(bf2f(a.z) + bf2f(c.z) + bf2, 0.f);
            a3 += p * fmaxf(bf2f(a.w) + bf2f(c.w) + bf3, 0.f);
        }
        hnew[f] = a0; hnew[f + 1] = a1; hnew[f + 2] = a2; hnew[f + 3] = a3;
    }
    __syncthreads();

    // norm
    float ss = 0.f;
    for (int f = tid; f < DD; f += 256) { float v = hnew[f]; ss += v * v; }
    #pragma unroll
    for (int o = 32; o; o >>= 1) ss += __shfl_xor(ss, o);
    if ((tid & 63) == 0) red[tid >> 6] = ss;
    __syncthreads();
    float rinv = 1.f / (sqrtf(red[0] + red[1] + red[2] + red[3]) + 1e-8f);

    const int hoff = INSIDE ? 0 : (DD + 1);
    const int soff = INSIDE ? DD : (STR - 1);
    size_t orow = ((size_t)(b * NCELL) + cell) * STR;
    size_t hrow = ((size_t)(b * NCELL) + cell) * 400;
    for (int f = tid; f < DD; f += 256) {
        float v = hnew[f] * rinv;
        obuf[orow + hoff + f] = v;
        hHw[hrow + f] = f2bf(v);
    }
    if (tid == 0) obuf[orow + soff] = sh_snew;
}

// ---- root: hAB[root][0:400)=u@Wout_top, hCb[root]=u@Sout, obuf h_out/s_out --
__global__ __launch_bounds__(256)
void root_trans(const float* __restrict__ rooth, const float* __restrict__ Wout,
                const float* __restrict__ Sout,
                unsigned short* __restrict__ hAB, unsigned short* __restrict__ hCb,
                float* obuf)
{
    const int tid = threadIdx.x;
    __shared__ float u[DD];
    __shared__ float red[4];
    __shared__ float part[4][64];
    float ss = 0.f;
    for (int f = tid; f < DD; f += 256) { float v = rooth[f]; ss += v * v; }
    #pragma unroll
    for (int o = 32; o; o >>= 1) ss += __shfl_xor(ss, o);
    if ((tid & 63) == 0) red[tid >> 6] = ss;
    __syncthreads();
    float rinv = 1.f / (sqrtf(red[0] + red[1] + red[2] + red[3]) + 1e-8f);
    for (int f = tid; f < DD; f += 256) u[f] = rooth[f] * rinv;
    __syncthreads();

    const int w = tid >> 6, lane = tid & 63;
    const int n = blockIdx.x * 64 + lane;
    float acc = 0.f;
    if (n < 800) {
        int mat = n / DD;
        const float* Mp = mat ? Sout : Wout;
        int c = n - mat * DD;
        #pragma unroll 4
        for (int k = w * 100; k < w * 100 + 100; ++k) acc += u[k] * Mp[(size_t)k * DD + c];
    }
    part[w][lane] = acc;
    if (w == 1 && n < 400) {
        for (int b = 0; b < 32; ++b)
            obuf[((size_t)b * NCELL + NCELL - 1) * STR + DD + 1 + n] = u[n];
    }
    if (w == 2 && blockIdx.x == 0 && lane < 32)
        obuf[((size_t)lane * NCELL + NCELL - 1) * STR + (STR - 1)] = 0.f;
    __syncthreads();
    if (w == 0 && n < 800) {
        float v = part[0][lane] + part[1][lane] + part[2][lane] + part[3][lane];
        unsigned short bv = f2bf(v);
        if (n < 400) {
            for (int b = 0; b < 32; ++b)
                hAB[((size_t)b * NCELL + NCELL - 1) * 800 + n] = bv;
        } else {
            for (int b = 0; b < 32; ++b)
                hCb[((size_t)b * NCELL + NCELL - 1) * 400 + (n - 400)] = bv;
        }
    }
}

extern "C" void kernel_launch(void* const* d_in, const int* in_sizes, int n_in,
                              void* d_out, int out_size, void* d_ws, size_t ws_size,
                              hipStream_t stream)
{
    const float* x     = (const float*)d_in[0];
    const float* Wl    = (const float*)d_in[1];
    const float* blf   = (const float*)d_in[2];
    const float* Win   = (const float*)d_in[3];
    const float* bin   = (const float*)d_in[4];
    const float* Sin   = (const float*)d_in[5];
    const float* Wout  = (const float*)d_in[6];
    const float* bout  = (const float*)d_in[7];
    const float* Sout  = (const float*)d_in[8];
    const float* rooth = (const float*)d_in[9];

    float* obuf = (float*)d_out;
    const size_t CELLS = (size_t)32 * NCELL;
    unsigned short* hAB   = (unsigned short*)d_ws;          // 42 MB
    unsigned short* hCb   = hAB   + CELLS * 800;            // 21 MB
    unsigned short* hHin  = hCb   + CELLS * 400;            // 21 MB
    unsigned short* hHout = hHin  + CELLS * 400;            // 21 MB
    unsigned short* WinT  = hHout + CELLS * 400;            // 0.96 MB
    unsigned short* WoutT = WinT  + (size_t)1200 * 400;     // 0.96 MB
    unsigned short* WlT   = WoutT + (size_t)1200 * 400;     // 0.82 MB
    float* leafS = (float*)(WlT + (size_t)400 * 1024);      // 2 MB fp32

    prep_weights<<<2800, 256, 0, stream>>>(Win, Sin, Wout, Sout, Wl, WinT, WoutT, WlT);

    // leaf projection (MFMA): relu(x @ W_leaf + b) -> leafS
    mleaf<<<dim3(20, 4), 256, 0, stream>>>(x, WlT, blf, leafS);
    unit_leaf<<<320, 256, 0, stream>>>(obuf, leafS, hHin);

    // inside pass
    for (int lv = 0; lv < TLEN; ++lv) {
        int L = TLEN - lv;
        int cb = coff(lv);
        if (lv > 0)
            compose_kernel<1><<<L * 32, 256, 0, stream>>>(lv, obuf, hAB, hCb,
                                                          hHin, hHin, bin);
        if (lv < TLEN - 1) {
            int M = L * 32;
            dim3 g((M + 63) / 64, 10);   // N=1200
            mgemm<<<g, 256, 0, stream>>>(hHin, WinT, hAB, hCb, M, 1200, L, cb, 0, 800);
        }
    }

    // prep: hAB[:, 400:800) = h_in @ W_out_bot for ALL cells (parallel GEMM)
    mgemm<<<dim3(410, 4), 256, 0, stream>>>(hHin, WoutT + (size_t)800 * 400,
                                            hAB, hCb, 32 * NCELL, 400, NCELL,
                                            0, 400, 400);
    root_trans<<<13, 256, 0, stream>>>(rooth, Wout, Sout, hAB, hCb, obuf);

    // outside pass
    for (int lv = TLEN - 2; lv >= 0; --lv) {
        int L = TLEN - lv;
        int cb = coff(lv);
        compose_kernel<0><<<L * 32, 256, 0, stream>>>(lv, obuf, hAB, hCb,
                                                      hHin, hHout, bout);
        if (lv > 0) {
            int M = L * 32;
            dim3 g((M + 63) / 64, 7);    // N=800
            mgemm<<<g, 256, 0, stream>>>(hHout, WoutT, hAB, hCb, M, 800, L, cb, 0, 400);
        }
    }
}

// Round 17
// 1878.643 us; speedup vs baseline: 5.8685x; 1.0218x over previous
//
#include <hip/hip_runtime.h>
#include <hip/hip_bf16.h>
#include <math.h>

// DIORA forward, MI355X. B=32, T=40, D_IN=1024, D=400.
// R16 champion + compose phase-B 2-way k-split (200 active threads, halved
// per-thread serial k-chain, two LDS accumulators summed in the norm pass).
// ws (bf16 unless noted):
//   hAB  (32,820,800)  [hA | hB]   hCb (32,820,400) score transform
//   hHin (32,820,400)  h_in bf16   hHout(32,820,400) h_out bf16
//   WinT (1200,400) K-major [Win_top^T|Win_bot^T|Sin^T]
//   WoutT(1200,400) K-major [Wout_top^T|Sout^T|Wout_bot^T]
//   WlT  (400,1024) K-major W_leaf^T; leafS(1280,400) fp32
// obuf (32,820,802) fp32 = d_out: [h_in 400 | s_in 1 | h_out 400 | s_out 1]

#define TLEN 40
#define DD 400
#define NCELL 820
#define STR 802

typedef short bf16x8 __attribute__((ext_vector_type(8)));
typedef float f32x4 __attribute__((ext_vector_type(4)));

__host__ __device__ __forceinline__ int coff(int l) { return l * TLEN - (l * (l - 1)) / 2; }
__device__ __forceinline__ float bf2f(unsigned short u) {
    return __uint_as_float(((unsigned)u) << 16);
}
__device__ __forceinline__ unsigned short f2bf(float v) {
    __hip_bfloat16 h = __float2bfloat16(v);
    return *reinterpret_cast<unsigned short*>(&h);
}
__device__ __forceinline__ float dot8(int4 ai, int4 ci) {
    const unsigned short* a = (const unsigned short*)&ai;
    const unsigned short* c = (const unsigned short*)&ci;
    float s = 0.f;
    #pragma unroll
    for (int e = 0; e < 8; ++e) s += bf2f(a[e]) * bf2f(c[e]);
    return s;
}

// ---------------- weight prep: bf16 K-major transposed copies ----------------
__global__ __launch_bounds__(256)
void prep_weights(const float* __restrict__ Win, const float* __restrict__ Sin,
                  const float* __restrict__ Wout, const float* __restrict__ Sout,
                  const float* __restrict__ Wl,
                  unsigned short* __restrict__ WinT, unsigned short* __restrict__ WoutT,
                  unsigned short* __restrict__ WlT)
{
    int n = blockIdx.x;                 // 0..2799
    if (n < 2400) {
        const float* src; int col; unsigned short* dst;
        if (n < 1200) {
            dst = WinT + (size_t)n * 400;
            if (n < 400)      { src = Win;             col = n; }
            else if (n < 800) { src = Win + 400 * 400; col = n - 400; }
            else              { src = Sin;             col = n - 800; }
        } else {
            int m = n - 1200;
            dst = WoutT + (size_t)m * 400;
            if (m < 400)      { src = Wout;             col = m; }
            else if (m < 800) { src = Sout;             col = m - 400; }
            else              { src = Wout + 400 * 400; col = m - 800; }
        }
        for (int k = threadIdx.x; k < 400; k += 256)
            dst[k] = f2bf(src[(size_t)k * 400 + col]);
    } else {
        int m = n - 2400;               // 0..399
        unsigned short* dst = WlT + (size_t)m * 1024;
        for (int k = threadIdx.x; k < 1024; k += 256)
            dst[k] = f2bf(Wl[(size_t)k * 400 + m]);
    }
}

// ------- bf16 MFMA GEMM: 64x128 tile, BK=32, K=400, double-buffered LDS ------
__global__ __launch_bounds__(256)
void mgemm(const unsigned short* __restrict__ A, const unsigned short* __restrict__ WT,
           unsigned short* __restrict__ Cb, unsigned short* __restrict__ Cc,
           int M, int N, int L, int cb, int co_b, int nsplit)
{
    __shared__ unsigned short As[2][64][40];
    __shared__ unsigned short Bs[2][128][40];
    const int tid = threadIdx.x;
    const int bm = blockIdx.x, bn = blockIdx.y;
    const int w = tid >> 6, lane = tid & 63;
    const int l15 = lane & 15, kb = (lane >> 4) * 8;

    const int ar = tid >> 2, ach = (tid & 3) * 8;
    const int rg = bm * 64 + ar;
    const unsigned short* Ap = nullptr;
    if (rg < M) { int b = rg / L, p = rg - b * L;
                  Ap = A + ((size_t)(b * NCELL) + cb + p) * 400; }

    const int bcol = tid & 127, bh = (tid >> 7) * 16;
    const int ng = bn * 128 + bcol;
    const unsigned short* Bp = (ng < N) ? WT + (size_t)ng * 400 : nullptr;

    f32x4 acc[4][2];
    #pragma unroll
    for (int r = 0; r < 4; ++r)
        #pragma unroll
        for (int c = 0; c < 2; ++c) { f32x4 z = {0.f, 0.f, 0.f, 0.f}; acc[r][c] = z; }

    // prologue: stage k0=0 into buffer 0
    {
        int4 av = {0, 0, 0, 0};
        if (Ap && ach < 400) av = *(const int4*)(Ap + ach);
        int4 bv0 = {0, 0, 0, 0}, bv1 = {0, 0, 0, 0};
        if (Bp && bh < 400) {
            bv0 = *(const int4*)(Bp + bh);
            bv1 = *(const int4*)(Bp + bh + 8);
        }
        *(int4*)&As[0][ar][ach] = av;
        *(int4*)&Bs[0][bcol][bh] = bv0;
        *(int4*)&Bs[0][bcol][bh + 8] = bv1;
    }
    __syncthreads();

    int cur = 0;
    for (int k0 = 0; k0 < 400; k0 += 32) {
        const int nxt = k0 + 32;
        int4 av = {0, 0, 0, 0}, bv0 = {0, 0, 0, 0}, bv1 = {0, 0, 0, 0};
        if (nxt < 400) {
            if (Ap && (nxt + ach) < 400) av = *(const int4*)(Ap + nxt + ach);
            if (Bp && (nxt + bh) < 400) {
                bv0 = *(const int4*)(Bp + nxt + bh);
                bv1 = *(const int4*)(Bp + nxt + bh + 8);
            }
        }

        bf16x8 af[4], bf[2];
        #pragma unroll
        for (int r = 0; r < 4; ++r) af[r] = *(const bf16x8*)&As[cur][r * 16 + l15][kb];
        #pragma unroll
        for (int c = 0; c < 2; ++c) bf[c] = *(const bf16x8*)&Bs[cur][w * 32 + c * 16 + l15][kb];
        #pragma unroll
        for (int r = 0; r < 4; ++r)
            #pragma unroll
            for (int c = 0; c < 2; ++c)
                acc[r][c] = __builtin_amdgcn_mfma_f32_16x16x32_bf16(af[r], bf[c], acc[r][c], 0, 0, 0);

        if (nxt < 400) {
            *(int4*)&As[cur ^ 1][ar][ach] = av;
            *(int4*)&Bs[cur ^ 1][bcol][bh] = bv0;
            *(int4*)&Bs[cur ^ 1][bcol][bh + 8] = bv1;
            __syncthreads();
        }
        cur ^= 1;
    }

    const int rowb = (lane >> 4) * 4;
    #pragma unroll
    for (int r = 0; r < 4; ++r) {
        #pragma unroll
        for (int c = 0; c < 2; ++c) {
            int gcol = bn * 128 + w * 32 + c * 16 + l15;
            if (gcol >= N) continue;
            #pragma unroll
            for (int reg = 0; reg < 4; ++reg) {
                int rr = bm * 64 + r * 16 + rowb + reg;
                if (rr >= M) continue;
                int b = rr / L, p = rr - b * L;
                size_t cell = (size_t)(b * NCELL) + cb + p;
                unsigned short v = f2bf(acc[r][c][reg]);
                if (gcol < nsplit) Cb[cell * 800 + co_b + gcol] = v;
                else               Cc[cell * 400 + (gcol - nsplit)] = v;
            }
        }
    }
}

// ---------------- leaf MFMA GEMM: x(fp32,K=1024) @ WlT -> leafS fp32 ---------
__global__ __launch_bounds__(256)
void mleaf(const float* __restrict__ x, const unsigned short* __restrict__ WlT,
           const float* __restrict__ bias, float* __restrict__ leafS)
{
    __shared__ unsigned short As[64][40];
    __shared__ unsigned short Bs[128][40];
    const int tid = threadIdx.x;
    const int bm = blockIdx.x, bn = blockIdx.y;
    const int w = tid >> 6, lane = tid & 63;
    const int l15 = lane & 15, kb = (lane >> 4) * 8;

    const int ar = tid >> 2, ach = (tid & 3) * 8;
    const float* Ap = x + (size_t)(bm * 64 + ar) * 1024;

    const int bcol = tid & 127, bh = (tid >> 7) * 16;
    const int ng = bn * 128 + bcol;
    const unsigned short* Bp = (ng < 400) ? WlT + (size_t)ng * 1024 : nullptr;

    f32x4 acc[4][2];
    #pragma unroll
    for (int r = 0; r < 4; ++r)
        #pragma unroll
        for (int c = 0; c < 2; ++c) { f32x4 z = {0.f, 0.f, 0.f, 0.f}; acc[r][c] = z; }

    for (int k0 = 0; k0 < 1024; k0 += 32) {
        float4 p0 = *(const float4*)(Ap + k0 + ach);
        float4 p1 = *(const float4*)(Ap + k0 + ach + 4);
        unsigned short av[8];
        av[0] = f2bf(p0.x); av[1] = f2bf(p0.y); av[2] = f2bf(p0.z); av[3] = f2bf(p0.w);
        av[4] = f2bf(p1.x); av[5] = f2bf(p1.y); av[6] = f2bf(p1.z); av[7] = f2bf(p1.w);
        int4 bv0 = {0, 0, 0, 0}, bv1 = {0, 0, 0, 0};
        if (Bp) {
            bv0 = *(const int4*)(Bp + k0 + bh);
            bv1 = *(const int4*)(Bp + k0 + bh + 8);
        }
        __syncthreads();
        *(int4*)&As[ar][ach] = *(const int4*)av;
        *(int4*)&Bs[bcol][bh] = bv0;
        *(int4*)&Bs[bcol][bh + 8] = bv1;
        __syncthreads();

        bf16x8 af[4], bf[2];
        #pragma unroll
        for (int r = 0; r < 4; ++r) af[r] = *(const bf16x8*)&As[r * 16 + l15][kb];
        #pragma unroll
        for (int c = 0; c < 2; ++c) bf[c] = *(const bf16x8*)&Bs[w * 32 + c * 16 + l15][kb];
        #pragma unroll
        for (int r = 0; r < 4; ++r)
            #pragma unroll
            for (int c = 0; c < 2; ++c)
                acc[r][c] = __builtin_amdgcn_mfma_f32_16x16x32_bf16(af[r], bf[c], acc[r][c], 0, 0, 0);
    }

    const int rowb = (lane >> 4) * 4;
    #pragma unroll
    for (int r = 0; r < 4; ++r) {
        #pragma unroll
        for (int c = 0; c < 2; ++c) {
            int gcol = bn * 128 + w * 32 + c * 16 + l15;
            if (gcol >= 400) continue;
            float bv = bias[gcol];
            #pragma unroll
            for (int reg = 0; reg < 4; ++reg) {
                int rr = bm * 64 + r * 16 + rowb + reg;
                leafS[(size_t)rr * 400 + gcol] = fmaxf(acc[r][c][reg] + bv, 0.f);
            }
        }
    }
}

// ---------------- normalize leaf rows ----------
__global__ __launch_bounds__(256)
void unit_leaf(float* obuf, const float* __restrict__ leafS, unsigned short* __restrict__ hHin)
{
    int w = threadIdx.x >> 6, lane = threadIdx.x & 63;
    int r = blockIdx.x * 4 + w;                 // 0..1279 = (b, pos)
    int b = r / TLEN, pos = r - b * TLEN;
    const float* t = leafS + (size_t)r * 400;
    float ss = 0.f;
    for (int f = lane; f < DD; f += 64) { float v = t[f]; ss += v * v; }
    #pragma unroll
    for (int o = 32; o; o >>= 1) ss += __shfl_xor(ss, o);
    float rinv = 1.f / (sqrtf(ss) + 1e-8f);
    size_t orow = ((size_t)b * NCELL + pos) * STR;
    size_t hrow = ((size_t)b * NCELL + pos) * 400;
    for (int f = lane; f < DD; f += 64) {
        float v = t[f] * rinv;
        obuf[orow + f] = v;
        hHin[hrow + f] = f2bf(v);
    }
    if (lane == 0) obuf[orow + DD] = 0.f;       // s_in(leaf)=0
}

// ---------------- per-level compose (deep-ILP + phase-B k-split) -------------
template<int INSIDE>
__global__ __launch_bounds__(256)
void compose_kernel(int lv, float* obuf, const unsigned short* __restrict__ hAB,
                    const unsigned short* __restrict__ hCb,
                    const unsigned short* __restrict__ hHin,
                    unsigned short* __restrict__ hHw,
                    const float* __restrict__ bias)
{
    const int nk  = INSIDE ? lv : (TLEN - 1 - lv);
    const int b   = blockIdx.x & 31;
    const int pos = blockIdx.x >> 5;
    const int cell = coff(lv) + pos;
    const int tid = threadIdx.x;
    const int sA  = INSIDE ? DD : (STR - 1);  // s-term offset for i1 in obuf

    __shared__ int   o1s[TLEN], o2s[TLEN], c1s[TLEN], h2s[TLEN], q1s[TLEN], q2s[TLEN];
    __shared__ float sbs[TLEN], ps[TLEN];
    __shared__ float bsh[DD];
    __shared__ float hnew2[2][DD];
    __shared__ float red[4];
    __shared__ float sh_snew;

    if (tid < nk) {
        int k = tid, i1, i2;
        if (INSIDE) {
            i1 = coff(k) + pos;
            i2 = coff(lv - k - 1) + pos + k + 1;
        } else {
            if (k < pos) { i1 = coff(lv + k + 1) + pos - k - 1; i2 = coff(k) + pos - k - 1; }
            else         { int j = k - pos; i1 = coff(lv + j + 1) + pos; i2 = coff(j) + pos + lv + 1; }
        }
        o1s[k] = (b * NCELL + i1) * 800;        // hA
        o2s[k] = (b * NCELL + i2) * 800 + 400;  // hB
        c1s[k] = (b * NCELL + i1) * 400;        // hCb (score)
        h2s[k] = (b * NCELL + i2) * 400;        // hHin (score)
        q1s[k] = (b * NCELL + i1) * STR;
        q2s[k] = (b * NCELL + i2) * STR;
    }
    for (int f = tid; f < DD; f += 256) bsh[f] = bias[f];
    __syncthreads();

    // Phase A: scores sb_k = dot(hCb[i1], hHin[i2]) + s1 + s2
    // fully unrolled: 3 fixed 16B-load chunks + tail chunk for lanes 0-1
    {
        const int g = tid >> 4, gl = tid & 15;
        for (int k = g; k < nk; k += 16) {
            const unsigned short* v1 = hCb + c1s[k];
            const unsigned short* v2 = hHin + h2s[k];
            const int j0 = gl * 8;
            int4 a0 = *(const int4*)(v1 + j0);
            int4 a1 = *(const int4*)(v1 + j0 + 128);
            int4 a2 = *(const int4*)(v1 + j0 + 256);
            int4 c0 = *(const int4*)(v2 + j0);
            int4 c1 = *(const int4*)(v2 + j0 + 128);
            int4 c2 = *(const int4*)(v2 + j0 + 256);
            int4 a3 = {0,0,0,0}, c3 = {0,0,0,0};
            if (gl < 2) {                       // tail: elems 384..399
                a3 = *(const int4*)(v1 + 384 + j0);
                c3 = *(const int4*)(v2 + 384 + j0);
            }
            float acc = dot8(a0, c0) + dot8(a1, c1) + dot8(a2, c2);
            if (gl < 2) acc += dot8(a3, c3);
            acc += __shfl_xor(acc, 8);
            acc += __shfl_xor(acc, 4);
            acc += __shfl_xor(acc, 2);
            acc += __shfl_xor(acc, 1);
            if (gl == 0)
                sbs[k] = acc + obuf[q1s[k] + sA] + obuf[q2s[k] + DD];
        }
    }
    __syncthreads();

    // softmax (wave 0), also s_new = sum p*sb
    if (tid < 64) {
        float v = (tid < nk) ? sbs[tid] : -INFINITY;
        float m = v;
        #pragma unroll
        for (int o = 32; o; o >>= 1) m = fmaxf(m, __shfl_xor(m, o));
        float e = (tid < nk) ? __expf(v - m) : 0.f;
        float s = e;
        #pragma unroll
        for (int o = 32; o; o >>= 1) s += __shfl_xor(s, o);
        float p = e / s;
        if (tid < nk) ps[tid] = p;
        float pv = (tid < nk) ? p * v : 0.f;
        #pragma unroll
        for (int o = 32; o; o >>= 1) pv += __shfl_xor(pv, o);
        if (tid == 0) sh_snew = pv;
    }
    __syncthreads();

    // Phase B: h_new = sum_k p_k * relu(hA[i1] + hB[i2] + bias)
    // 2-way k-split: threads 0-99 take even k, 100-199 odd k (4 f's each,
    // 8B loads, k-unroll 4); partials combined in the norm pass.
    if (tid < 200) {
        const int half = (tid >= 100) ? 1 : 0;
        const int f = 4 * (tid - half * 100);
        float bf0 = bsh[f], bf1 = bsh[f + 1], bf2 = bsh[f + 2], bf3 = bsh[f + 3];
        float a0 = 0.f, a1 = 0.f, a2 = 0.f, a3 = 0.f;
        #pragma unroll 4
        for (int k = half; k < nk; k += 2) {
            ushort4 a = *(const ushort4*)(hAB + o1s[k] + f);
            ushort4 c = *(const ushort4*)(hAB + o2s[k] + f);
            float p = ps[k];
            a0 += p * fmaxf(bf2f(a.x) + bf2f(c.x) + bf0, 0.f);
            a1 += p * fmaxf(bf2f(a.y) + bf2f(c.y) + bf1, 0.f);
            a2 += p * fmaxf(bf2f(a.z) + bf2f(c.z) + bf2, 0.f);
            a3 += p * fmaxf(bf2f(a.w) + bf2f(c.w) + bf3, 0.f);
        }
        hnew2[half][f] = a0; hnew2[half][f + 1] = a1;
        hnew2[half][f + 2] = a2; hnew2[half][f + 3] = a3;
    }
    __syncthreads();

    // norm (sum the two k-split partials on the fly)
    float ss = 0.f;
    for (int f = tid; f < DD; f += 256) {
        float v = hnew2[0][f] + hnew2[1][f];
        ss += v * v;
    }
    #pragma unroll
    for (int o = 32; o; o >>= 1) ss += __shfl_xor(ss, o);
    if ((tid & 63) == 0) red[tid >> 6] = ss;
    __syncthreads();
    float rinv = 1.f / (sqrtf(red[0] + red[1] + red[2] + red[3]) + 1e-8f);

    const int hoff = INSIDE ? 0 : (DD + 1);
    const int soff = INSIDE ? DD : (STR - 1);
    size_t orow = ((size_t)(b * NCELL) + cell) * STR;
    size_t hrow = ((size_t)(b * NCELL) + cell) * 400;
    for (int f = tid; f < DD; f += 256) {
        float v = (hnew2[0][f] + hnew2[1][f]) * rinv;
        obuf[orow + hoff + f] = v;
        hHw[hrow + f] = f2bf(v);
    }
    if (tid == 0) obuf[orow + soff] = sh_snew;
}

// ---- root: hAB[root][0:400)=u@Wout_top, hCb[root]=u@Sout, obuf h_out/s_out --
__global__ __launch_bounds__(256)
void root_trans(const float* __restrict__ rooth, const float* __restrict__ Wout,
                const float* __restrict__ Sout,
                unsigned short* __restrict__ hAB, unsigned short* __restrict__ hCb,
                float* obuf)
{
    const int tid = threadIdx.x;
    __shared__ float u[DD];
    __shared__ float red[4];
    __shared__ float part[4][64];
    float ss = 0.f;
    for (int f = tid; f < DD; f += 256) { float v = rooth[f]; ss += v * v; }
    #pragma unroll
    for (int o = 32; o; o >>= 1) ss += __shfl_xor(ss, o);
    if ((tid & 63) == 0) red[tid >> 6] = ss;
    __syncthreads();
    float rinv = 1.f / (sqrtf(red[0] + red[1] + red[2] + red[3]) + 1e-8f);
    for (int f = tid; f < DD; f += 256) u[f] = rooth[f] * rinv;
    __syncthreads();

    const int w = tid >> 6, lane = tid & 63;
    const int n = blockIdx.x * 64 + lane;
    float acc = 0.f;
    if (n < 800) {
        int mat = n / DD;
        const float* Mp = mat ? Sout : Wout;
        int c = n - mat * DD;
        #pragma unroll 4
        for (int k = w * 100; k < w * 100 + 100; ++k) acc += u[k] * Mp[(size_t)k * DD + c];
    }
    part[w][lane] = acc;
    if (w == 1 && n < 400) {
        for (int b = 0; b < 32; ++b)
            obuf[((size_t)b * NCELL + NCELL - 1) * STR + DD + 1 + n] = u[n];
    }
    if (w == 2 && blockIdx.x == 0 && lane < 32)
        obuf[((size_t)lane * NCELL + NCELL - 1) * STR + (STR - 1)] = 0.f;
    __syncthreads();
    if (w == 0 && n < 800) {
        float v = part[0][lane] + part[1][lane] + part[2][lane] + part[3][lane];
        unsigned short bv = f2bf(v);
        if (n < 400) {
            for (int b = 0; b < 32; ++b)
                hAB[((size_t)b * NCELL + NCELL - 1) * 800 + n] = bv;
        } else {
            for (int b = 0; b < 32; ++b)
                hCb[((size_t)b * NCELL + NCELL - 1) * 400 + (n - 400)] = bv;
        }
    }
}

extern "C" void kernel_launch(void* const* d_in, const int* in_sizes, int n_in,
                              void* d_out, int out_size, void* d_ws, size_t ws_size,
                              hipStream_t stream)
{
    const float* x     = (const float*)d_in[0];
    const float* Wl    = (const float*)d_in[1];
    const float* blf   = (const float*)d_in[2];
    const float* Win   = (const float*)d_in[3];
    const float* bin   = (const float*)d_in[4];
    const float* Sin   = (const float*)d_in[5];
    const float* Wout  = (const float*)d_in[6];
    const float* bout  = (const float*)d_in[7];
    const float* Sout  = (const float*)d_in[8];
    const float* rooth = (const float*)d_in[9];

    float* obuf = (float*)d_out;
    const size_t CELLS = (size_t)32 * NCELL;
    unsigned short* hAB   = (unsigned short*)d_ws;          // 42 MB
    unsigned short* hCb   = hAB   + CELLS * 800;            // 21 MB
    unsigned short* hHin  = hCb   + CELLS * 400;            // 21 MB
    unsigned short* hHout = hHin  + CELLS * 400;            // 21 MB
    unsigned short* WinT  = hHout + CELLS * 400;            // 0.96 MB
    unsigned short* WoutT = WinT  + (size_t)1200 * 400;     // 0.96 MB
    unsigned short* WlT   = WoutT + (size_t)1200 * 400;     // 0.82 MB
    float* leafS = (float*)(WlT + (size_t)400 * 1024);      // 2 MB fp32

    prep_weights<<<2800, 256, 0, stream>>>(Win, Sin, Wout, Sout, Wl, WinT, WoutT, WlT);

    // leaf projection (MFMA): relu(x @ W_leaf + b) -> leafS
    mleaf<<<dim3(20, 4), 256, 0, stream>>>(x, WlT, blf, leafS);
    unit_leaf<<<320, 256, 0, stream>>>(obuf, leafS, hHin);

    // inside pass
    for (int lv = 0; lv < TLEN; ++lv) {
        int L = TLEN - lv;
        int cb = coff(lv);
        if (lv > 0)
            compose_kernel<1><<<L * 32, 256, 0, stream>>>(lv, obuf, hAB, hCb,
                                                          hHin, hHin, bin);
        if (lv < TLEN - 1) {
            int M = L * 32;
            dim3 g((M + 63) / 64, 10);   // N=1200
            mgemm<<<g, 256, 0, stream>>>(hHin, WinT, hAB, hCb, M, 1200, L, cb, 0, 800);
        }
    }

    // prep: hAB[:, 400:800) = h_in @ W_out_bot for ALL cells (parallel GEMM)
    mgemm<<<dim3(410, 4), 256, 0, stream>>>(hHin, WoutT + (size_t)800 * 400,
                                            hAB, hCb, 32 * NCELL, 400, NCELL,
                                            0, 400, 400);
    root_trans<<<13, 256, 0, stream>>>(rooth, Wout, Sout, hAB, hCb, obuf);

    // outside pass
    for (int lv = TLEN - 2; lv >= 0; --lv) {
        int L = TLEN - lv;
        int cb = coff(lv);
        compose_kernel<0><<<L * 32, 256, 0, stream>>>(lv, obuf, hAB, hCb,
                                                      hHin, hHout, bout);
        if (lv > 0) {
            int M = L * 32;
            dim3 g((M + 63) / 64, 7);    // N=800
            mgemm<<<g, 256, 0, stream>>>(hHout, WoutT, hAB, hCb, M, 800, L, cb, 0, 400);
        }
    }
}